// Round 1
// baseline (3520.675 us; speedup 1.0000x reference)
//
#include <hip/hip_runtime.h>

// ---------------------------------------------------------------------------
// 3-layer GCN on MI355X.
// Per call: build deg/dinv + CSR (bucketed by dst) once, then per layer:
//   GEMM (X@W, fp32, LDS-tiled)  ->  atomic-free aggregation (1 wave / node)
//   with fused bias + BN(eval) + ReLU epilogue.
// ---------------------------------------------------------------------------

// ---------------- degree / dinv ----------------
__global__ __launch_bounds__(256) void k_deg(const int* __restrict__ ei,
                                             int* __restrict__ deg, int E) {
    int e = blockIdx.x * 256 + threadIdx.x;
    if (e < E) atomicAdd(&deg[ei[E + e]], 1);   // dst row of edge_index
}

__global__ __launch_bounds__(256) void k_dinv(const int* __restrict__ deg,
                                              float* __restrict__ dinv, int n) {
    int i = blockIdx.x * 256 + threadIdx.x;
    if (i < n) dinv[i] = rsqrtf((float)deg[i] + 1.0f);   // +1 self loop
}

// ---------------- exclusive scan of deg -> row_ptr (2-level) ----------------
__global__ __launch_bounds__(256) void k_scan1(const int* __restrict__ deg,
                                               int* __restrict__ row_ptr,
                                               int* __restrict__ bsums, int n) {
    __shared__ int s[256];
    int i = blockIdx.x * 256 + threadIdx.x;
    int v = (i < n) ? deg[i] : 0;
    s[threadIdx.x] = v;
    __syncthreads();
    for (int off = 1; off < 256; off <<= 1) {
        int add = (threadIdx.x >= off) ? s[threadIdx.x - off] : 0;
        __syncthreads();
        s[threadIdx.x] += add;
        __syncthreads();
    }
    if (i < n) row_ptr[i] = s[threadIdx.x] - v;          // exclusive
    if (threadIdx.x == 255) bsums[blockIdx.x] = s[255];  // block total
}

__global__ __launch_bounds__(512) void k_scan2(const int* __restrict__ bsums,
                                               int* __restrict__ boffs, int nb) {
    __shared__ int s[512];
    int t = threadIdx.x;
    int v = (t < nb) ? bsums[t] : 0;
    s[t] = v;
    __syncthreads();
    for (int off = 1; off < 512; off <<= 1) {
        int add = (t >= off) ? s[t - off] : 0;
        __syncthreads();
        s[t] += add;
        __syncthreads();
    }
    if (t < nb) boffs[t] = s[t] - v;                     // exclusive
}

__global__ __launch_bounds__(256) void k_scan3(int* __restrict__ row_ptr,
                                               const int* __restrict__ boffs, int n) {
    int i = blockIdx.x * 256 + threadIdx.x;
    if (i < n) row_ptr[i] += boffs[blockIdx.x];
}

// ---------------- CSR fill (bucket edges by dst) ----------------
__global__ __launch_bounds__(256) void k_fill(const int* __restrict__ ei,
                                              const int* __restrict__ row_ptr,
                                              int* __restrict__ cursor,
                                              int* __restrict__ csr, int E) {
    int e = blockIdx.x * 256 + threadIdx.x;
    if (e < E) {
        int s = ei[e];
        int d = ei[E + e];
        int p = row_ptr[d] + atomicAdd(&cursor[d], 1);
        csr[p] = s;
    }
}

// ---------------- fp32 GEMM: H[n,DOUT] = X[n,128] @ W[128,DOUT] ----------------
// W fully staged in LDS; X tile staged in LDS; 4x4 register tile per thread.
template <int DOUT>
__global__ __launch_bounds__(256) void k_gemm(const float* __restrict__ X,
                                              const float* __restrict__ W,
                                              float* __restrict__ H, int n,
                                              int ntiles) {
    constexpr int CG   = DOUT / 4;        // col groups of 4
    constexpr int ROWS = 1024 / CG;       // 32 (DOUT=128) or 64 (DOUT=64)
    constexpr int RS   = (DOUT == 128) ? 128 : 132;  // pad row stride for DOUT=64
    __shared__ float Ws[128 * DOUT];
    __shared__ float Xs[ROWS * RS];

    const int t = threadIdx.x;
    for (int i = t; i < 128 * DOUT; i += 256) Ws[i] = W[i];

    const int tx = t % CG, ty = t / CG;
    const int r0 = ty * 4, c0 = tx * 4;

    for (int tile = blockIdx.x; tile < ntiles; tile += gridDim.x) {
        const int rbase = tile * ROWS;
        __syncthreads();  // protect Xs (and Ws on first iter)
        for (int l = t; l < ROWS * 128; l += 256) {
            int r = l >> 7, k = l & 127;
            int gr = rbase + r;
            Xs[r * RS + k] = (gr < n) ? X[(size_t)gr * 128 + k] : 0.f;
        }
        __syncthreads();

        float acc[4][4] = {};
        for (int k = 0; k < 128; k += 4) {
            float4 xv[4], wv[4];
#pragma unroll
            for (int i = 0; i < 4; i++)
                xv[i] = *(const float4*)&Xs[(r0 + i) * RS + k];
#pragma unroll
            for (int kk = 0; kk < 4; kk++)
                wv[kk] = *(const float4*)&Ws[(k + kk) * DOUT + c0];
#pragma unroll
            for (int kk = 0; kk < 4; kk++) {
                float w0 = wv[kk].x, w1 = wv[kk].y, w2 = wv[kk].z, w3 = wv[kk].w;
#pragma unroll
                for (int i = 0; i < 4; i++) {
                    float xs = (kk == 0) ? xv[i].x
                             : (kk == 1) ? xv[i].y
                             : (kk == 2) ? xv[i].z
                                         : xv[i].w;
                    acc[i][0] = fmaf(xs, w0, acc[i][0]);
                    acc[i][1] = fmaf(xs, w1, acc[i][1]);
                    acc[i][2] = fmaf(xs, w2, acc[i][2]);
                    acc[i][3] = fmaf(xs, w3, acc[i][3]);
                }
            }
        }
#pragma unroll
        for (int i = 0; i < 4; i++) {
            int gr = rbase + r0 + i;
            if (gr < n) {
                *(float4*)&H[(size_t)gr * DOUT + c0] =
                    make_float4(acc[i][0], acc[i][1], acc[i][2], acc[i][3]);
            }
        }
    }
}

// ---------------- aggregation: 1 wave per node, atomic-free ----------------
// out[i] = dinv[i]*( sum_{e in-edges} dinv[src]*h[src] + dinv[i]*h[i] ) + b
// then optional BN(eval)+ReLU.
template <int DOUT, bool BNRELU>
__global__ __launch_bounds__(256) void k_agg(
    const float* __restrict__ H, float* __restrict__ O,
    const int* __restrict__ csr, const int* __restrict__ row_ptr,
    const int* __restrict__ deg, const float* __restrict__ dinv,
    const float* __restrict__ bias, const float* __restrict__ gam,
    const float* __restrict__ bet, const float* __restrict__ rm,
    const float* __restrict__ rv, int n) {
    int node = blockIdx.x * 4 + (threadIdx.x >> 6);
    if (node >= n) return;
    int lane  = threadIdx.x & 63;
    int start = row_ptr[node];
    int cnt   = deg[node];
    float di  = dinv[node];

    if constexpr (DOUT == 128) {
        int c = lane * 2;
        float2 hs = *(const float2*)(H + (size_t)node * 128 + c);
        float ax = di * hs.x, ay = di * hs.y;
        for (int e = 0; e < cnt; ++e) {
            int s   = csr[start + e];       // wave-uniform broadcast load
            float w = dinv[s];
            float2 hv = *(const float2*)(H + (size_t)s * 128 + c);
            ax = fmaf(w, hv.x, ax);
            ay = fmaf(w, hv.y, ay);
        }
        float ox = fmaf(di, ax, bias[c]);
        float oy = fmaf(di, ay, bias[c + 1]);
        if constexpr (BNRELU) {
            float sx = gam[c] * rsqrtf(rv[c] + 1e-5f);
            float sy = gam[c + 1] * rsqrtf(rv[c + 1] + 1e-5f);
            ox = fmaxf(fmaf(ox - rm[c], sx, bet[c]), 0.f);
            oy = fmaxf(fmaf(oy - rm[c + 1], sy, bet[c + 1]), 0.f);
        }
        *(float2*)(O + (size_t)node * 128 + c) = make_float2(ox, oy);
    } else {  // DOUT == 64, no BN/ReLU (final layer)
        int c = lane;
        float a = di * H[(size_t)node * 64 + c];
        for (int e = 0; e < cnt; ++e) {
            int s   = csr[start + e];
            float w = dinv[s];
            a = fmaf(w, H[(size_t)s * 64 + c], a);
        }
        O[(size_t)node * 64 + c] = fmaf(di, a, bias[c]);
    }
}

// ---------------------------------------------------------------------------
extern "C" void kernel_launch(void* const* d_in, const int* in_sizes, int n_in,
                              void* d_out, int out_size, void* d_ws, size_t ws_size,
                              hipStream_t stream) {
    const float* x   = (const float*)d_in[0];
    const int*   ei  = (const int*)d_in[1];
    const float* W1  = (const float*)d_in[2];
    const float* b1  = (const float*)d_in[3];
    const float* g1  = (const float*)d_in[4];
    const float* be1 = (const float*)d_in[5];
    const float* rm1 = (const float*)d_in[6];
    const float* rv1 = (const float*)d_in[7];
    const float* W2  = (const float*)d_in[8];
    const float* b2  = (const float*)d_in[9];
    const float* g2  = (const float*)d_in[10];
    const float* be2 = (const float*)d_in[11];
    const float* rm2 = (const float*)d_in[12];
    const float* rv2 = (const float*)d_in[13];
    const float* W3  = (const float*)d_in[14];
    const float* b3  = (const float*)d_in[15];

    const int n = in_sizes[0] / 128;
    const int E = in_sizes[1] / 2;

    // ---- workspace carve-up (aligned to 256B) ----
    char*  w   = (char*)d_ws;
    size_t off = 0;
    auto take  = [&](size_t bytes) -> char* {
        char* p = w + off;
        off += (bytes + 255) & ~(size_t)255;
        return p;
    };
    int*   deg    = (int*)take((size_t)n * 4);
    int*   cursor = (int*)take((size_t)n * 4);
    int*   rowp   = (int*)take((size_t)n * 4);
    float* dinv   = (float*)take((size_t)n * 4);
    const int NB  = (n + 255) / 256;
    int*   bsums  = (int*)take((size_t)NB * 4);
    int*   boffs  = (int*)take((size_t)NB * 4);
    int*   csr    = (int*)take((size_t)E * 4);
    float* bufA   = (float*)take((size_t)n * 128 * 4);
    float* bufB   = (float*)take((size_t)n * 128 * 4);
    (void)ws_size; (void)n_in; (void)out_size;

    // ---- graph preprocessing (identical every call; ws is re-poisoned) ----
    hipMemsetAsync(deg, 0, (size_t)n * 4, stream);
    hipMemsetAsync(cursor, 0, (size_t)n * 4, stream);
    const int egrid = (E + 255) / 256;
    k_deg<<<egrid, 256, 0, stream>>>(ei, deg, E);
    k_dinv<<<NB, 256, 0, stream>>>(deg, dinv, n);
    k_scan1<<<NB, 256, 0, stream>>>(deg, rowp, bsums, n);
    k_scan2<<<1, 512, 0, stream>>>(bsums, boffs, NB);
    k_scan3<<<NB, 256, 0, stream>>>(rowp, boffs, n);
    k_fill<<<egrid, 256, 0, stream>>>(ei, rowp, cursor, csr, E);

    // ---- 3 GCN layers ----
    const int nt128 = (n + 31) / 32;
    const int nt64  = (n + 63) / 64;
    const int g128  = nt128 < 512 ? nt128 : 512;
    const int g64   = nt64 < 512 ? nt64 : 512;
    const int agrid = (n + 3) / 4;

    k_gemm<128><<<g128, 256, 0, stream>>>(x, W1, bufA, n, nt128);
    k_agg<128, true><<<agrid, 256, 0, stream>>>(bufA, bufB, csr, rowp, deg, dinv,
                                                b1, g1, be1, rm1, rv1, n);
    k_gemm<128><<<g128, 256, 0, stream>>>(bufB, W2, bufA, n, nt128);
    k_agg<128, true><<<agrid, 256, 0, stream>>>(bufA, bufB, csr, rowp, deg, dinv,
                                                b2, g2, be2, rm2, rv2, n);
    k_gemm<64><<<g64, 256, 0, stream>>>(bufB, W3, bufA, n, nt64);
    k_agg<64, false><<<agrid, 256, 0, stream>>>(bufA, (float*)d_out, csr, rowp, deg,
                                                dinv, b3, nullptr, nullptr, nullptr,
                                                nullptr, n);
}

// Round 3
// 988.666 us; speedup vs baseline: 3.5610x; 3.5610x over previous
//
#include <hip/hip_runtime.h>

// ---------------------------------------------------------------------------
// 3-layer GCN on MI355X.
// Per call: build deg/dinv + CSR (bucketed by dst) once, then per layer:
//   GEMM (X@W, fp32, LDS-tiled)  ->  atomic-free aggregation (1 wave / node)
//   with fused bias + BN(eval) + ReLU epilogue.
// R1 change: k_gemm K-loop `#pragma unroll 2` — R0's implicit full unroll
// blew past 256 VGPRs and spilled ~3.3 GB/dispatch to scratch (rocprof:
// FETCH 1.8GB, WRITE 1.5GB, VALUBusy 4.4%).
// R2: resubmit of R1 (bench never ran — GPU acquisition timeout).
// ---------------------------------------------------------------------------

// ---------------- degree / dinv ----------------
__global__ __launch_bounds__(256) void k_deg(const int* __restrict__ ei,
                                             int* __restrict__ deg, int E) {
    int e = blockIdx.x * 256 + threadIdx.x;
    if (e < E) atomicAdd(&deg[ei[E + e]], 1);   // dst row of edge_index
}

__global__ __launch_bounds__(256) void k_dinv(const int* __restrict__ deg,
                                              float* __restrict__ dinv, int n) {
    int i = blockIdx.x * 256 + threadIdx.x;
    if (i < n) dinv[i] = rsqrtf((float)deg[i] + 1.0f);   // +1 self loop
}

// ---------------- exclusive scan of deg -> row_ptr (2-level) ----------------
__global__ __launch_bounds__(256) void k_scan1(const int* __restrict__ deg,
                                               int* __restrict__ row_ptr,
                                               int* __restrict__ bsums, int n) {
    __shared__ int s[256];
    int i = blockIdx.x * 256 + threadIdx.x;
    int v = (i < n) ? deg[i] : 0;
    s[threadIdx.x] = v;
    __syncthreads();
    for (int off = 1; off < 256; off <<= 1) {
        int add = (threadIdx.x >= off) ? s[threadIdx.x - off] : 0;
        __syncthreads();
        s[threadIdx.x] += add;
        __syncthreads();
    }
    if (i < n) row_ptr[i] = s[threadIdx.x] - v;          // exclusive
    if (threadIdx.x == 255) bsums[blockIdx.x] = s[255];  // block total
}

__global__ __launch_bounds__(512) void k_scan2(const int* __restrict__ bsums,
                                               int* __restrict__ boffs, int nb) {
    __shared__ int s[512];
    int t = threadIdx.x;
    int v = (t < nb) ? bsums[t] : 0;
    s[t] = v;
    __syncthreads();
    for (int off = 1; off < 512; off <<= 1) {
        int add = (t >= off) ? s[t - off] : 0;
        __syncthreads();
        s[t] += add;
        __syncthreads();
    }
    if (t < nb) boffs[t] = s[t] - v;                     // exclusive
}

__global__ __launch_bounds__(256) void k_scan3(int* __restrict__ row_ptr,
                                               const int* __restrict__ boffs, int n) {
    int i = blockIdx.x * 256 + threadIdx.x;
    if (i < n) row_ptr[i] += boffs[blockIdx.x];
}

// ---------------- CSR fill (bucket edges by dst) ----------------
__global__ __launch_bounds__(256) void k_fill(const int* __restrict__ ei,
                                              const int* __restrict__ row_ptr,
                                              int* __restrict__ cursor,
                                              int* __restrict__ csr, int E) {
    int e = blockIdx.x * 256 + threadIdx.x;
    if (e < E) {
        int s = ei[e];
        int d = ei[E + e];
        int p = row_ptr[d] + atomicAdd(&cursor[d], 1);
        csr[p] = s;
    }
}

// ---------------- fp32 GEMM: H[n,DOUT] = X[n,128] @ W[128,DOUT] ----------------
// W fully staged in LDS; X tile staged in LDS; 4x4 register tile per thread.
// X reads are same-address broadcast within a wave (free); W reads are a
// contiguous 512B panel (conflict-free, SQ_LDS_BANK_CONFLICT==0 measured).
template <int DOUT>
__global__ __launch_bounds__(256, 2) void k_gemm(const float* __restrict__ X,
                                                 const float* __restrict__ W,
                                                 float* __restrict__ H, int n,
                                                 int ntiles) {
    constexpr int CG   = DOUT / 4;        // col groups of 4
    constexpr int ROWS = 1024 / CG;       // 32 (DOUT=128) or 64 (DOUT=64)
    constexpr int RS   = (DOUT == 128) ? 128 : 132;  // pad row stride for DOUT=64
    __shared__ float Ws[128 * DOUT];
    __shared__ float Xs[ROWS * RS];

    const int t = threadIdx.x;
    for (int i = t; i < 128 * DOUT; i += 256) Ws[i] = W[i];

    const int tx = t % CG, ty = t / CG;
    const int r0 = ty * 4, c0 = tx * 4;

    for (int tile = blockIdx.x; tile < ntiles; tile += gridDim.x) {
        const int rbase = tile * ROWS;
        __syncthreads();  // protect Xs (and Ws on first iter)
        for (int l = t; l < ROWS * 128; l += 256) {
            int r = l >> 7, k = l & 127;
            int gr = rbase + r;
            Xs[r * RS + k] = (gr < n) ? X[(size_t)gr * 128 + k] : 0.f;
        }
        __syncthreads();

        float acc[4][4] = {};
#pragma unroll 2           // R1: cap unroll — full unroll spilled to scratch
        for (int k = 0; k < 128; k += 4) {
            float4 xv[4], wv[4];
#pragma unroll
            for (int i = 0; i < 4; i++)
                xv[i] = *(const float4*)&Xs[(r0 + i) * RS + k];
#pragma unroll
            for (int kk = 0; kk < 4; kk++)
                wv[kk] = *(const float4*)&Ws[(k + kk) * DOUT + c0];
#pragma unroll
            for (int kk = 0; kk < 4; kk++) {
                float w0 = wv[kk].x, w1 = wv[kk].y, w2 = wv[kk].z, w3 = wv[kk].w;
#pragma unroll
                for (int i = 0; i < 4; i++) {
                    float xs = (kk == 0) ? xv[i].x
                             : (kk == 1) ? xv[i].y
                             : (kk == 2) ? xv[i].z
                                         : xv[i].w;
                    acc[i][0] = fmaf(xs, w0, acc[i][0]);
                    acc[i][1] = fmaf(xs, w1, acc[i][1]);
                    acc[i][2] = fmaf(xs, w2, acc[i][2]);
                    acc[i][3] = fmaf(xs, w3, acc[i][3]);
                }
            }
        }
#pragma unroll
        for (int i = 0; i < 4; i++) {
            int gr = rbase + r0 + i;
            if (gr < n) {
                *(float4*)&H[(size_t)gr * DOUT + c0] =
                    make_float4(acc[i][0], acc[i][1], acc[i][2], acc[i][3]);
            }
        }
    }
}

// ---------------- aggregation: 1 wave per node, atomic-free ----------------
// out[i] = dinv[i]*( sum_{e in-edges} dinv[src]*h[src] + dinv[i]*h[i] ) + b
// then optional BN(eval)+ReLU.
template <int DOUT, bool BNRELU>
__global__ __launch_bounds__(256) void k_agg(
    const float* __restrict__ H, float* __restrict__ O,
    const int* __restrict__ csr, const int* __restrict__ row_ptr,
    const int* __restrict__ deg, const float* __restrict__ dinv,
    const float* __restrict__ bias, const float* __restrict__ gam,
    const float* __restrict__ bet, const float* __restrict__ rm,
    const float* __restrict__ rv, int n) {
    int node = blockIdx.x * 4 + (threadIdx.x >> 6);
    if (node >= n) return;
    int lane  = threadIdx.x & 63;
    int start = row_ptr[node];
    int cnt   = deg[node];
    float di  = dinv[node];

    if constexpr (DOUT == 128) {
        int c = lane * 2;
        float2 hs = *(const float2*)(H + (size_t)node * 128 + c);
        float ax = di * hs.x, ay = di * hs.y;
        for (int e = 0; e < cnt; ++e) {
            int s   = csr[start + e];       // wave-uniform broadcast load
            float w = dinv[s];
            float2 hv = *(const float2*)(H + (size_t)s * 128 + c);
            ax = fmaf(w, hv.x, ax);
            ay = fmaf(w, hv.y, ay);
        }
        float ox = fmaf(di, ax, bias[c]);
        float oy = fmaf(di, ay, bias[c + 1]);
        if constexpr (BNRELU) {
            float sx = gam[c] * rsqrtf(rv[c] + 1e-5f);
            float sy = gam[c + 1] * rsqrtf(rv[c + 1] + 1e-5f);
            ox = fmaxf(fmaf(ox - rm[c], sx, bet[c]), 0.f);
            oy = fmaxf(fmaf(oy - rm[c + 1], sy, bet[c + 1]), 0.f);
        }
        *(float2*)(O + (size_t)node * 128 + c) = make_float2(ox, oy);
    } else {  // DOUT == 64, no BN/ReLU (final layer)
        int c = lane;
        float a = di * H[(size_t)node * 64 + c];
        for (int e = 0; e < cnt; ++e) {
            int s   = csr[start + e];
            float w = dinv[s];
            a = fmaf(w, H[(size_t)s * 64 + c], a);
        }
        O[(size_t)node * 64 + c] = fmaf(di, a, bias[c]);
    }
}

// ---------------------------------------------------------------------------
extern "C" void kernel_launch(void* const* d_in, const int* in_sizes, int n_in,
                              void* d_out, int out_size, void* d_ws, size_t ws_size,
                              hipStream_t stream) {
    const float* x   = (const float*)d_in[0];
    const int*   ei  = (const int*)d_in[1];
    const float* W1  = (const float*)d_in[2];
    const float* b1  = (const float*)d_in[3];
    const float* g1  = (const float*)d_in[4];
    const float* be1 = (const float*)d_in[5];
    const float* rm1 = (const float*)d_in[6];
    const float* rv1 = (const float*)d_in[7];
    const float* W2  = (const float*)d_in[8];
    const float* b2  = (const float*)d_in[9];
    const float* g2  = (const float*)d_in[10];
    const float* be2 = (const float*)d_in[11];
    const float* rm2 = (const float*)d_in[12];
    const float* rv2 = (const float*)d_in[13];
    const float* W3  = (const float*)d_in[14];
    const float* b3  = (const float*)d_in[15];

    const int n = in_sizes[0] / 128;
    const int E = in_sizes[1] / 2;

    // ---- workspace carve-up (aligned to 256B) ----
    char*  w   = (char*)d_ws;
    size_t off = 0;
    auto take  = [&](size_t bytes) -> char* {
        char* p = w + off;
        off += (bytes + 255) & ~(size_t)255;
        return p;
    };
    int*   deg    = (int*)take((size_t)n * 4);
    int*   cursor = (int*)take((size_t)n * 4);
    int*   rowp   = (int*)take((size_t)n * 4);
    float* dinv   = (float*)take((size_t)n * 4);
    const int NB  = (n + 255) / 256;
    int*   bsums  = (int*)take((size_t)NB * 4);
    int*   boffs  = (int*)take((size_t)NB * 4);
    int*   csr    = (int*)take((size_t)E * 4);
    float* bufA   = (float*)take((size_t)n * 128 * 4);
    float* bufB   = (float*)take((size_t)n * 128 * 4);
    (void)ws_size; (void)n_in; (void)out_size;

    // ---- graph preprocessing (identical every call; ws is re-poisoned) ----
    hipMemsetAsync(deg, 0, (size_t)n * 4, stream);
    hipMemsetAsync(cursor, 0, (size_t)n * 4, stream);
    const int egrid = (E + 255) / 256;
    k_deg<<<egrid, 256, 0, stream>>>(ei, deg, E);
    k_dinv<<<NB, 256, 0, stream>>>(deg, dinv, n);
    k_scan1<<<NB, 256, 0, stream>>>(deg, rowp, bsums, n);
    k_scan2<<<1, 512, 0, stream>>>(bsums, boffs, NB);
    k_scan3<<<NB, 256, 0, stream>>>(rowp, boffs, n);
    k_fill<<<egrid, 256, 0, stream>>>(ei, rowp, cursor, csr, E);

    // ---- 3 GCN layers ----
    const int nt128 = (n + 31) / 32;
    const int nt64  = (n + 63) / 64;
    const int g128  = nt128 < 512 ? nt128 : 512;
    const int g64   = nt64 < 512 ? nt64 : 512;
    const int agrid = (n + 3) / 4;

    k_gemm<128><<<g128, 256, 0, stream>>>(x, W1, bufA, n, nt128);
    k_agg<128, true><<<agrid, 256, 0, stream>>>(bufA, bufB, csr, rowp, deg, dinv,
                                                b1, g1, be1, rm1, rv1, n);
    k_gemm<128><<<g128, 256, 0, stream>>>(bufB, W2, bufA, n, nt128);
    k_agg<128, true><<<agrid, 256, 0, stream>>>(bufA, bufB, csr, rowp, deg, dinv,
                                                b2, g2, be2, rm2, rv2, n);
    k_gemm<64><<<g64, 256, 0, stream>>>(bufB, W3, bufA, n, nt64);
    k_agg<64, false><<<agrid, 256, 0, stream>>>(bufA, (float*)d_out, csr, rowp, deg,
                                                dinv, b3, nullptr, nullptr, nullptr,
                                                nullptr, n);
}

// Round 4
// 817.008 us; speedup vs baseline: 4.3092x; 1.2101x over previous
//
#include <hip/hip_runtime.h>

// ---------------------------------------------------------------------------
// 3-layer GCN on MI355X.
// R1: k_gemm `#pragma unroll 2` fixed 3.3GB/dispatch scratch spill (3520->988us).
// R3: aggregation was the new dominator (179us, latency-bound: VALUBusy 16%,
//     serial 16-iter edge loop, 1 outstanding gather/wave). Changes:
//     (a) GEMM epilogue pre-scales rows by dinv -> Hs = dinv*(XW); edge loop
//         loses the per-edge dinv load+mul: agg_i = dinv_i*(Hs_i + sum Hs_s)+b.
//     (b) edge loop unrolled x4 with 4 independent accumulators, csr read as
//         aligned int4 (4 gathers in flight per wave).
//     (c) adjacency padded to multiple of 4 with sentinel edges -> zero row n
//         of Hs (no remainder loop, no divergence).
// ---------------------------------------------------------------------------

// ---------------- degree ----------------
__global__ __launch_bounds__(256) void k_deg(const int* __restrict__ ei,
                                             int* __restrict__ deg, int E) {
    int e = blockIdx.x * 256 + threadIdx.x;
    if (e < E) atomicAdd(&deg[ei[E + e]], 1);   // dst row of edge_index
}

// dinv + padded degree (round deg up to multiple of 4)
__global__ __launch_bounds__(256) void k_prep(const int* __restrict__ deg,
                                              float* __restrict__ dinv,
                                              int* __restrict__ degp, int n) {
    int i = blockIdx.x * 256 + threadIdx.x;
    if (i < n) {
        int d = deg[i];
        dinv[i] = rsqrtf((float)d + 1.0f);   // +1 self loop
        degp[i] = (d + 3) & ~3;
    }
}

// ---------------- exclusive scan of degp -> row_ptr (2-level) ----------------
__global__ __launch_bounds__(256) void k_scan1(const int* __restrict__ degp,
                                               int* __restrict__ row_ptr,
                                               int* __restrict__ bsums, int n) {
    __shared__ int s[256];
    int i = blockIdx.x * 256 + threadIdx.x;
    int v = (i < n) ? degp[i] : 0;
    s[threadIdx.x] = v;
    __syncthreads();
    for (int off = 1; off < 256; off <<= 1) {
        int add = (threadIdx.x >= off) ? s[threadIdx.x - off] : 0;
        __syncthreads();
        s[threadIdx.x] += add;
        __syncthreads();
    }
    if (i < n) row_ptr[i] = s[threadIdx.x] - v;          // exclusive
    if (threadIdx.x == 255) bsums[blockIdx.x] = s[255];  // block total
}

__global__ __launch_bounds__(512) void k_scan2(const int* __restrict__ bsums,
                                               int* __restrict__ boffs, int nb) {
    __shared__ int s[512];
    int t = threadIdx.x;
    int v = (t < nb) ? bsums[t] : 0;
    s[t] = v;
    __syncthreads();
    for (int off = 1; off < 512; off <<= 1) {
        int add = (t >= off) ? s[t - off] : 0;
        __syncthreads();
        s[t] += add;
        __syncthreads();
    }
    if (t < nb) boffs[t] = s[t] - v;                     // exclusive
}

__global__ __launch_bounds__(256) void k_scan3(int* __restrict__ row_ptr,
                                               const int* __restrict__ boffs, int n) {
    int i = blockIdx.x * 256 + threadIdx.x;
    if (i < n) row_ptr[i] += boffs[blockIdx.x];
}

// ---------------- CSR fill (bucket edges by dst) ----------------
__global__ __launch_bounds__(256) void k_fill(const int* __restrict__ ei,
                                              const int* __restrict__ row_ptr,
                                              int* __restrict__ cursor,
                                              int* __restrict__ csr, int E) {
    int e = blockIdx.x * 256 + threadIdx.x;
    if (e < E) {
        int s = ei[e];
        int d = ei[E + e];
        int p = row_ptr[d] + atomicAdd(&cursor[d], 1);
        csr[p] = s;
    }
}

// pad entries [deg, degp) with sentinel index n (zero row of Hs)
__global__ __launch_bounds__(256) void k_pad(const int* __restrict__ deg,
                                             const int* __restrict__ degp,
                                             const int* __restrict__ row_ptr,
                                             int* __restrict__ csr, int n) {
    int i = blockIdx.x * 256 + threadIdx.x;
    if (i < n) {
        int start = row_ptr[i];
        int d = deg[i], dp = degp[i];
        for (int j = d; j < dp; ++j) csr[start + j] = n;
    }
}

// ---------------- fp32 GEMM: Hs[n,DOUT] = dinv * (X[n,128] @ W[128,DOUT]) ----
// W fully staged in LDS; X tile staged in LDS; 4x4 register tile per thread.
template <int DOUT>
__global__ __launch_bounds__(256, 2) void k_gemm(const float* __restrict__ X,
                                                 const float* __restrict__ W,
                                                 const float* __restrict__ dinv,
                                                 float* __restrict__ H, int n,
                                                 int ntiles) {
    constexpr int CG   = DOUT / 4;        // col groups of 4
    constexpr int ROWS = 1024 / CG;       // 32 (DOUT=128) or 64 (DOUT=64)
    constexpr int RS   = (DOUT == 128) ? 128 : 132;  // pad row stride for DOUT=64
    __shared__ float Ws[128 * DOUT];
    __shared__ float Xs[ROWS * RS];

    const int t = threadIdx.x;
    for (int i = t; i < 128 * DOUT; i += 256) Ws[i] = W[i];

    const int tx = t % CG, ty = t / CG;
    const int r0 = ty * 4, c0 = tx * 4;

    for (int tile = blockIdx.x; tile < ntiles; tile += gridDim.x) {
        const int rbase = tile * ROWS;
        __syncthreads();  // protect Xs (and Ws on first iter)
        for (int l = t; l < ROWS * 128; l += 256) {
            int r = l >> 7, k = l & 127;
            int gr = rbase + r;
            Xs[r * RS + k] = (gr < n) ? X[(size_t)gr * 128 + k] : 0.f;
        }
        __syncthreads();

        float acc[4][4] = {};
#pragma unroll 2           // R1: cap unroll — full unroll spilled to scratch
        for (int k = 0; k < 128; k += 4) {
            float4 xv[4], wv[4];
#pragma unroll
            for (int i = 0; i < 4; i++)
                xv[i] = *(const float4*)&Xs[(r0 + i) * RS + k];
#pragma unroll
            for (int kk = 0; kk < 4; kk++)
                wv[kk] = *(const float4*)&Ws[(k + kk) * DOUT + c0];
#pragma unroll
            for (int kk = 0; kk < 4; kk++) {
                float w0 = wv[kk].x, w1 = wv[kk].y, w2 = wv[kk].z, w3 = wv[kk].w;
#pragma unroll
                for (int i = 0; i < 4; i++) {
                    float xs = (kk == 0) ? xv[i].x
                             : (kk == 1) ? xv[i].y
                             : (kk == 2) ? xv[i].z
                                         : xv[i].w;
                    acc[i][0] = fmaf(xs, w0, acc[i][0]);
                    acc[i][1] = fmaf(xs, w1, acc[i][1]);
                    acc[i][2] = fmaf(xs, w2, acc[i][2]);
                    acc[i][3] = fmaf(xs, w3, acc[i][3]);
                }
            }
        }
#pragma unroll
        for (int i = 0; i < 4; i++) {
            int gr = rbase + r0 + i;
            if (gr < n) {
                float di = dinv[gr];     // R3: pre-scale rows by dinv
                *(float4*)&H[(size_t)gr * DOUT + c0] =
                    make_float4(di * acc[i][0], di * acc[i][1],
                                di * acc[i][2], di * acc[i][3]);
            }
        }
    }
}

// ---------------- aggregation: 1 wave per node, atomic-free ----------------
// Hs rows are pre-scaled by dinv.  out_i = dinv_i*(Hs_i + sum_{s} Hs_s) + b
// (pad edges point at zero row n).  Then optional BN(eval)+ReLU.
template <int DOUT, bool BNRELU>
__global__ __launch_bounds__(256) void k_agg(
    const float* __restrict__ Hs, float* __restrict__ O,
    const int* __restrict__ csr, const int* __restrict__ row_ptr,
    const int* __restrict__ degp, const float* __restrict__ dinv,
    const float* __restrict__ bias, const float* __restrict__ gam,
    const float* __restrict__ bet, const float* __restrict__ rm,
    const float* __restrict__ rv, int n) {
    int node = blockIdx.x * 4 + (threadIdx.x >> 6);
    if (node >= n) return;
    int lane  = threadIdx.x & 63;
    int start = row_ptr[node];
    int cntp  = degp[node];             // multiple of 4
    float di  = dinv[node];

    if constexpr (DOUT == 128) {
        int c = lane * 2;
        float2 a0 = *(const float2*)(Hs + (size_t)node * 128 + c);  // self
        float2 a1 = {0.f, 0.f}, a2 = {0.f, 0.f}, a3 = {0.f, 0.f};
        for (int e = 0; e < cntp; e += 4) {
            int4 s4 = *(const int4*)&csr[start + e];   // 16B-aligned, uniform
            float2 h0 = *(const float2*)(Hs + (size_t)s4.x * 128 + c);
            float2 h1 = *(const float2*)(Hs + (size_t)s4.y * 128 + c);
            float2 h2 = *(const float2*)(Hs + (size_t)s4.z * 128 + c);
            float2 h3 = *(const float2*)(Hs + (size_t)s4.w * 128 + c);
            a0.x += h0.x; a0.y += h0.y;
            a1.x += h1.x; a1.y += h1.y;
            a2.x += h2.x; a2.y += h2.y;
            a3.x += h3.x; a3.y += h3.y;
        }
        float ax = (a0.x + a1.x) + (a2.x + a3.x);
        float ay = (a0.y + a1.y) + (a2.y + a3.y);
        float ox = fmaf(di, ax, bias[c]);
        float oy = fmaf(di, ay, bias[c + 1]);
        if constexpr (BNRELU) {
            float sx = gam[c] * rsqrtf(rv[c] + 1e-5f);
            float sy = gam[c + 1] * rsqrtf(rv[c + 1] + 1e-5f);
            ox = fmaxf(fmaf(ox - rm[c], sx, bet[c]), 0.f);
            oy = fmaxf(fmaf(oy - rm[c + 1], sy, bet[c + 1]), 0.f);
        }
        *(float2*)(O + (size_t)node * 128 + c) = make_float2(ox, oy);
    } else {  // DOUT == 64, no BN/ReLU (final layer)
        int c = lane;
        float a0 = Hs[(size_t)node * 64 + c];  // self
        float a1 = 0.f, a2 = 0.f, a3 = 0.f;
        for (int e = 0; e < cntp; e += 4) {
            int4 s4 = *(const int4*)&csr[start + e];
            a0 += Hs[(size_t)s4.x * 64 + c];
            a1 += Hs[(size_t)s4.y * 64 + c];
            a2 += Hs[(size_t)s4.z * 64 + c];
            a3 += Hs[(size_t)s4.w * 64 + c];
        }
        O[(size_t)node * 64 + c] = fmaf(di, (a0 + a1) + (a2 + a3), bias[c]);
    }
}

// ---------------------------------------------------------------------------
extern "C" void kernel_launch(void* const* d_in, const int* in_sizes, int n_in,
                              void* d_out, int out_size, void* d_ws, size_t ws_size,
                              hipStream_t stream) {
    const float* x   = (const float*)d_in[0];
    const int*   ei  = (const int*)d_in[1];
    const float* W1  = (const float*)d_in[2];
    const float* b1  = (const float*)d_in[3];
    const float* g1  = (const float*)d_in[4];
    const float* be1 = (const float*)d_in[5];
    const float* rm1 = (const float*)d_in[6];
    const float* rv1 = (const float*)d_in[7];
    const float* W2  = (const float*)d_in[8];
    const float* b2  = (const float*)d_in[9];
    const float* g2  = (const float*)d_in[10];
    const float* be2 = (const float*)d_in[11];
    const float* rm2 = (const float*)d_in[12];
    const float* rv2 = (const float*)d_in[13];
    const float* W3  = (const float*)d_in[14];
    const float* b3  = (const float*)d_in[15];

    const int n = in_sizes[0] / 128;
    const int E = in_sizes[1] / 2;

    // ---- workspace carve-up (aligned to 256B) ----
    char*  w   = (char*)d_ws;
    size_t off = 0;
    auto take  = [&](size_t bytes) -> char* {
        char* p = w + off;
        off += (bytes + 255) & ~(size_t)255;
        return p;
    };
    int*   deg    = (int*)take((size_t)n * 4);
    int*   degp   = (int*)take((size_t)n * 4);
    int*   cursor = (int*)take((size_t)n * 4);
    int*   rowp   = (int*)take((size_t)n * 4);
    float* dinv   = (float*)take((size_t)n * 4);
    const int NB  = (n + 255) / 256;
    int*   bsums  = (int*)take((size_t)NB * 4);
    int*   boffs  = (int*)take((size_t)NB * 4);
    int*   csr    = (int*)take((size_t)E * 4 + (size_t)n * 3 * 4 + 64);  // padded
    float* bufA   = (float*)take(((size_t)n + 1) * 128 * 4);  // +1 zero row
    float* bufB   = (float*)take(((size_t)n + 1) * 128 * 4);
    (void)ws_size; (void)n_in; (void)out_size;

    // ---- graph preprocessing (identical every call; ws is re-poisoned) ----
    hipMemsetAsync(deg, 0, (size_t)n * 4, stream);
    hipMemsetAsync(cursor, 0, (size_t)n * 4, stream);
    hipMemsetAsync(bufA + (size_t)n * 128, 0, 128 * 4, stream);  // zero row (128-case)
    const int egrid = (E + 255) / 256;
    k_deg<<<egrid, 256, 0, stream>>>(ei, deg, E);
    k_prep<<<NB, 256, 0, stream>>>(deg, dinv, degp, n);
    k_scan1<<<NB, 256, 0, stream>>>(degp, rowp, bsums, n);
    k_scan2<<<1, 512, 0, stream>>>(bsums, boffs, NB);
    k_scan3<<<NB, 256, 0, stream>>>(rowp, boffs, n);
    k_fill<<<egrid, 256, 0, stream>>>(ei, rowp, cursor, csr, E);
    k_pad<<<NB, 256, 0, stream>>>(deg, degp, rowp, csr, n);

    // ---- 3 GCN layers ----
    const int nt128 = (n + 31) / 32;
    const int nt64  = (n + 63) / 64;
    const int g128  = nt128 < 512 ? nt128 : 512;
    const int g64   = nt64 < 512 ? nt64 : 512;
    const int agrid = (n + 3) / 4;

    k_gemm<128><<<g128, 256, 0, stream>>>(x, W1, dinv, bufA, n, nt128);
    k_agg<128, true><<<agrid, 256, 0, stream>>>(bufA, bufB, csr, rowp, degp, dinv,
                                                b1, g1, be1, rm1, rv1, n);
    k_gemm<128><<<g128, 256, 0, stream>>>(bufB, W2, dinv, bufA, n, nt128);
    k_agg<128, true><<<agrid, 256, 0, stream>>>(bufA, bufB, csr, rowp, degp, dinv,
                                                b2, g2, be2, rm2, rv2, n);
    k_gemm<64><<<g64, 256, 0, stream>>>(bufB, W3, dinv, bufA, n, nt64);
    hipMemsetAsync(bufA + (size_t)n * 64, 0, 64 * 4, stream);    // zero row (64-case)
    k_agg<64, false><<<agrid, 256, 0, stream>>>(bufA, (float*)d_out, csr, rowp, degp,
                                                dinv, b3, nullptr, nullptr, nullptr,
                                                nullptr, n);
}

// Round 6
// 774.104 us; speedup vs baseline: 4.5481x; 1.0554x over previous
//
#include <hip/hip_runtime.h>

// ---------------------------------------------------------------------------
// 3-layer GCN on MI355X.
// R1: k_gemm `#pragma unroll 2` fixed 3.3GB/dispatch scratch spill (3520->988us).
// R3: dinv pre-scale into GEMM epilogue + agg unroll-4 + pad-4 (988->817us).
// R5: (a) agg unroll-8 / pad-8 (8 gathers in flight; was latency-bound at
//         VALUBusy 21%, 3.77 TB/s);
//     (b) gemm drops Xs LDS staging + per-tile barriers: X read directly from
//         global as ty-group broadcast float4 (streams via L1, row read once
//         per block), W stays in 64KB LDS. No __syncthreads in tile loop.
// R5-resubmit: R5 bench never ran (GPU acquisition timeout).
// ---------------------------------------------------------------------------

// ---------------- degree ----------------
__global__ __launch_bounds__(256) void k_deg(const int* __restrict__ ei,
                                             int* __restrict__ deg, int E) {
    int e = blockIdx.x * 256 + threadIdx.x;
    if (e < E) atomicAdd(&deg[ei[E + e]], 1);   // dst row of edge_index
}

// dinv + padded degree (round deg up to multiple of 8)
__global__ __launch_bounds__(256) void k_prep(const int* __restrict__ deg,
                                              float* __restrict__ dinv,
                                              int* __restrict__ degp, int n) {
    int i = blockIdx.x * 256 + threadIdx.x;
    if (i < n) {
        int d = deg[i];
        dinv[i] = rsqrtf((float)d + 1.0f);   // +1 self loop
        degp[i] = (d + 7) & ~7;
    }
}

// ---------------- exclusive scan of degp -> row_ptr (2-level) ----------------
__global__ __launch_bounds__(256) void k_scan1(const int* __restrict__ degp,
                                               int* __restrict__ row_ptr,
                                               int* __restrict__ bsums, int n) {
    __shared__ int s[256];
    int i = blockIdx.x * 256 + threadIdx.x;
    int v = (i < n) ? degp[i] : 0;
    s[threadIdx.x] = v;
    __syncthreads();
    for (int off = 1; off < 256; off <<= 1) {
        int add = (threadIdx.x >= off) ? s[threadIdx.x - off] : 0;
        __syncthreads();
        s[threadIdx.x] += add;
        __syncthreads();
    }
    if (i < n) row_ptr[i] = s[threadIdx.x] - v;          // exclusive
    if (threadIdx.x == 255) bsums[blockIdx.x] = s[255];  // block total
}

__global__ __launch_bounds__(512) void k_scan2(const int* __restrict__ bsums,
                                               int* __restrict__ boffs, int nb) {
    __shared__ int s[512];
    int t = threadIdx.x;
    int v = (t < nb) ? bsums[t] : 0;
    s[t] = v;
    __syncthreads();
    for (int off = 1; off < 512; off <<= 1) {
        int add = (t >= off) ? s[t - off] : 0;
        __syncthreads();
        s[t] += add;
        __syncthreads();
    }
    if (t < nb) boffs[t] = s[t] - v;                     // exclusive
}

__global__ __launch_bounds__(256) void k_scan3(int* __restrict__ row_ptr,
                                               const int* __restrict__ boffs, int n) {
    int i = blockIdx.x * 256 + threadIdx.x;
    if (i < n) row_ptr[i] += boffs[blockIdx.x];
}

// ---------------- CSR fill (bucket edges by dst) ----------------
__global__ __launch_bounds__(256) void k_fill(const int* __restrict__ ei,
                                              const int* __restrict__ row_ptr,
                                              int* __restrict__ cursor,
                                              int* __restrict__ csr, int E) {
    int e = blockIdx.x * 256 + threadIdx.x;
    if (e < E) {
        int s = ei[e];
        int d = ei[E + e];
        int p = row_ptr[d] + atomicAdd(&cursor[d], 1);
        csr[p] = s;
    }
}

// pad entries [deg, degp) with sentinel index n (zero row of Hs)
__global__ __launch_bounds__(256) void k_pad(const int* __restrict__ deg,
                                             const int* __restrict__ degp,
                                             const int* __restrict__ row_ptr,
                                             int* __restrict__ csr, int n) {
    int i = blockIdx.x * 256 + threadIdx.x;
    if (i < n) {
        int start = row_ptr[i];
        int d = deg[i], dp = degp[i];
        for (int j = d; j < dp; ++j) csr[start + j] = n;
    }
}

// ---------------- fp32 GEMM: Hs[n,DOUT] = dinv * (X[n,128] @ W[128,DOUT]) ----
// W fully staged in LDS (64/32 KB). X is NOT staged: each thread reads its 4
// rows directly from global as float4 — all lanes of a ty-group read the same
// address (broadcast coalesce) and each row streams through L1 once per block.
// No per-tile __syncthreads -> waves pipeline freely across tiles.
template <int DOUT>
__global__ __launch_bounds__(256, (DOUT == 128) ? 2 : 4)
void k_gemm(const float* __restrict__ X, const float* __restrict__ W,
            const float* __restrict__ dinv, float* __restrict__ H, int n,
            int ntiles) {
    constexpr int CG   = DOUT / 4;        // col groups of 4 (32 or 16)
    constexpr int ROWS = 1024 / CG;       // 32 (DOUT=128) or 64 (DOUT=64)
    __shared__ float Ws[128 * DOUT];

    const int t = threadIdx.x;
    for (int i = t; i < 128 * DOUT; i += 256) Ws[i] = W[i];
    __syncthreads();

    const int tx = t % CG, ty = t / CG;
    const int c0 = tx * 4;

    for (int tile = blockIdx.x; tile < ntiles; tile += gridDim.x) {
        const int rbase = tile * ROWS + ty * 4;
        const float* xr[4];
#pragma unroll
        for (int i = 0; i < 4; i++) {
            int gr = rbase + i;
            xr[i] = X + (size_t)(gr < n ? gr : n - 1) * 128;  // clamp (loads in-bounds)
        }

        float acc[4][4] = {};
#pragma unroll 2           // R1: cap unroll — full unroll spilled to scratch
        for (int k = 0; k < 128; k += 4) {
            float4 xv[4], wv[4];
#pragma unroll
            for (int i = 0; i < 4; i++)
                xv[i] = *(const float4*)(xr[i] + k);
#pragma unroll
            for (int kk = 0; kk < 4; kk++)
                wv[kk] = *(const float4*)&Ws[(k + kk) * DOUT + c0];
#pragma unroll
            for (int kk = 0; kk < 4; kk++) {
                float w0 = wv[kk].x, w1 = wv[kk].y, w2 = wv[kk].z, w3 = wv[kk].w;
#pragma unroll
                for (int i = 0; i < 4; i++) {
                    float xs = (kk == 0) ? xv[i].x
                             : (kk == 1) ? xv[i].y
                             : (kk == 2) ? xv[i].z
                                         : xv[i].w;
                    acc[i][0] = fmaf(xs, w0, acc[i][0]);
                    acc[i][1] = fmaf(xs, w1, acc[i][1]);
                    acc[i][2] = fmaf(xs, w2, acc[i][2]);
                    acc[i][3] = fmaf(xs, w3, acc[i][3]);
                }
            }
        }
#pragma unroll
        for (int i = 0; i < 4; i++) {
            int gr = rbase + i;
            if (gr < n) {
                float di = dinv[gr];     // R3: pre-scale rows by dinv
                *(float4*)&H[(size_t)gr * DOUT + c0] =
                    make_float4(di * acc[i][0], di * acc[i][1],
                                di * acc[i][2], di * acc[i][3]);
            }
        }
    }
}

// ---------------- aggregation: 1 wave per node, atomic-free ----------------
// Hs rows are pre-scaled by dinv.  out_i = dinv_i*(Hs_i + sum_{s} Hs_s) + b
// (pad edges point at zero row n).  Then optional BN(eval)+ReLU.
// R5: unroll-8 — two int4 index loads, 8 independent row gathers in flight.
template <int DOUT, bool BNRELU>
__global__ __launch_bounds__(256) void k_agg(
    const float* __restrict__ Hs, float* __restrict__ O,
    const int* __restrict__ csr, const int* __restrict__ row_ptr,
    const int* __restrict__ degp, const float* __restrict__ dinv,
    const float* __restrict__ bias, const float* __restrict__ gam,
    const float* __restrict__ bet, const float* __restrict__ rm,
    const float* __restrict__ rv, int n) {
    int node = blockIdx.x * 4 + (threadIdx.x >> 6);
    if (node >= n) return;
    int lane  = threadIdx.x & 63;
    int start = row_ptr[node];
    int cntp  = degp[node];             // multiple of 8
    float di  = dinv[node];

    if constexpr (DOUT == 128) {
        int c = lane * 2;
        float2 a[8];
        a[0] = *(const float2*)(Hs + (size_t)node * 128 + c);  // self
#pragma unroll
        for (int j = 1; j < 8; j++) a[j] = make_float2(0.f, 0.f);
        for (int e = 0; e < cntp; e += 8) {
            int4 sa = *(const int4*)&csr[start + e];       // 32B-aligned pair
            int4 sb = *(const int4*)&csr[start + e + 4];
            float2 h0 = *(const float2*)(Hs + (size_t)sa.x * 128 + c);
            float2 h1 = *(const float2*)(Hs + (size_t)sa.y * 128 + c);
            float2 h2 = *(const float2*)(Hs + (size_t)sa.z * 128 + c);
            float2 h3 = *(const float2*)(Hs + (size_t)sa.w * 128 + c);
            float2 h4 = *(const float2*)(Hs + (size_t)sb.x * 128 + c);
            float2 h5 = *(const float2*)(Hs + (size_t)sb.y * 128 + c);
            float2 h6 = *(const float2*)(Hs + (size_t)sb.z * 128 + c);
            float2 h7 = *(const float2*)(Hs + (size_t)sb.w * 128 + c);
            a[0].x += h0.x; a[0].y += h0.y;
            a[1].x += h1.x; a[1].y += h1.y;
            a[2].x += h2.x; a[2].y += h2.y;
            a[3].x += h3.x; a[3].y += h3.y;
            a[4].x += h4.x; a[4].y += h4.y;
            a[5].x += h5.x; a[5].y += h5.y;
            a[6].x += h6.x; a[6].y += h6.y;
            a[7].x += h7.x; a[7].y += h7.y;
        }
        float ax = ((a[0].x + a[1].x) + (a[2].x + a[3].x)) +
                   ((a[4].x + a[5].x) + (a[6].x + a[7].x));
        float ay = ((a[0].y + a[1].y) + (a[2].y + a[3].y)) +
                   ((a[4].y + a[5].y) + (a[6].y + a[7].y));
        float ox = fmaf(di, ax, bias[c]);
        float oy = fmaf(di, ay, bias[c + 1]);
        if constexpr (BNRELU) {
            float sx = gam[c] * rsqrtf(rv[c] + 1e-5f);
            float sy = gam[c + 1] * rsqrtf(rv[c + 1] + 1e-5f);
            ox = fmaxf(fmaf(ox - rm[c], sx, bet[c]), 0.f);
            oy = fmaxf(fmaf(oy - rm[c + 1], sy, bet[c + 1]), 0.f);
        }
        *(float2*)(O + (size_t)node * 128 + c) = make_float2(ox, oy);
    } else {  // DOUT == 64, no BN/ReLU (final layer)
        int c = lane;
        float a[8];
        a[0] = Hs[(size_t)node * 64 + c];  // self
#pragma unroll
        for (int j = 1; j < 8; j++) a[j] = 0.f;
        for (int e = 0; e < cntp; e += 8) {
            int4 sa = *(const int4*)&csr[start + e];
            int4 sb = *(const int4*)&csr[start + e + 4];
            a[0] += Hs[(size_t)sa.x * 64 + c];
            a[1] += Hs[(size_t)sa.y * 64 + c];
            a[2] += Hs[(size_t)sa.z * 64 + c];
            a[3] += Hs[(size_t)sa.w * 64 + c];
            a[4] += Hs[(size_t)sb.x * 64 + c];
            a[5] += Hs[(size_t)sb.y * 64 + c];
            a[6] += Hs[(size_t)sb.z * 64 + c];
            a[7] += Hs[(size_t)sb.w * 64 + c];
        }
        float s = ((a[0] + a[1]) + (a[2] + a[3])) + ((a[4] + a[5]) + (a[6] + a[7]));
        O[(size_t)node * 64 + c] = fmaf(di, s, bias[c]);
    }
}

// ---------------------------------------------------------------------------
extern "C" void kernel_launch(void* const* d_in, const int* in_sizes, int n_in,
                              void* d_out, int out_size, void* d_ws, size_t ws_size,
                              hipStream_t stream) {
    const float* x   = (const float*)d_in[0];
    const int*   ei  = (const int*)d_in[1];
    const float* W1  = (const float*)d_in[2];
    const float* b1  = (const float*)d_in[3];
    const float* g1  = (const float*)d_in[4];
    const float* be1 = (const float*)d_in[5];
    const float* rm1 = (const float*)d_in[6];
    const float* rv1 = (const float*)d_in[7];
    const float* W2  = (const float*)d_in[8];
    const float* b2  = (const float*)d_in[9];
    const float* g2  = (const float*)d_in[10];
    const float* be2 = (const float*)d_in[11];
    const float* rm2 = (const float*)d_in[12];
    const float* rv2 = (const float*)d_in[13];
    const float* W3  = (const float*)d_in[14];
    const float* b3  = (const float*)d_in[15];

    const int n = in_sizes[0] / 128;
    const int E = in_sizes[1] / 2;

    // ---- workspace carve-up (aligned to 256B) ----
    char*  w   = (char*)d_ws;
    size_t off = 0;
    auto take  = [&](size_t bytes) -> char* {
        char* p = w + off;
        off += (bytes + 255) & ~(size_t)255;
        return p;
    };
    int*   deg    = (int*)take((size_t)n * 4);
    int*   degp   = (int*)take((size_t)n * 4);
    int*   cursor = (int*)take((size_t)n * 4);
    int*   rowp   = (int*)take((size_t)n * 4);
    float* dinv   = (float*)take((size_t)n * 4);
    const int NB  = (n + 255) / 256;
    int*   bsums  = (int*)take((size_t)NB * 4);
    int*   boffs  = (int*)take((size_t)NB * 4);
    int*   csr    = (int*)take((size_t)E * 4 + (size_t)n * 7 * 4 + 64);  // pad-8
    float* bufA   = (float*)take(((size_t)n + 1) * 128 * 4);  // +1 zero row
    float* bufB   = (float*)take(((size_t)n + 1) * 128 * 4);
    (void)ws_size; (void)n_in; (void)out_size;

    // ---- graph preprocessing (identical every call; ws is re-poisoned) ----
    hipMemsetAsync(deg, 0, (size_t)n * 4, stream);
    hipMemsetAsync(cursor, 0, (size_t)n * 4, stream);
    hipMemsetAsync(bufA + (size_t)n * 128, 0, 128 * 4, stream);  // zero row (128-case)
    const int egrid = (E + 255) / 256;
    k_deg<<<egrid, 256, 0, stream>>>(ei, deg, E);
    k_prep<<<NB, 256, 0, stream>>>(deg, dinv, degp, n);
    k_scan1<<<NB, 256, 0, stream>>>(degp, rowp, bsums, n);
    k_scan2<<<1, 512, 0, stream>>>(bsums, boffs, NB);
    k_scan3<<<NB, 256, 0, stream>>>(rowp, boffs, n);
    k_fill<<<egrid, 256, 0, stream>>>(ei, rowp, cursor, csr, E);
    k_pad<<<NB, 256, 0, stream>>>(deg, degp, rowp, csr, n);

    // ---- 3 GCN layers ----
    const int nt128 = (n + 31) / 32;
    const int nt64  = (n + 63) / 64;
    const int g128  = nt128 < 512 ? nt128 : 512;
    const int g64   = nt64 < 512 ? nt64 : 512;
    const int agrid = (n + 3) / 4;

    k_gemm<128><<<g128, 256, 0, stream>>>(x, W1, dinv, bufA, n, nt128);
    k_agg<128, true><<<agrid, 256, 0, stream>>>(bufA, bufB, csr, rowp, degp, dinv,
                                                b1, g1, be1, rm1, rv1, n);
    k_gemm<128><<<g128, 256, 0, stream>>>(bufB, W2, dinv, bufA, n, nt128);
    k_agg<128, true><<<agrid, 256, 0, stream>>>(bufA, bufB, csr, rowp, degp, dinv,
                                                b2, g2, be2, rm2, rv2, n);
    k_gemm<64><<<g64, 256, 0, stream>>>(bufB, W3, dinv, bufA, n, nt64);
    hipMemsetAsync(bufA + (size_t)n * 64, 0, 64 * 4, stream);    // zero row (64-case)
    k_agg<64, false><<<agrid, 256, 0, stream>>>(bufA, (float*)d_out, csr, rowp, degp,
                                                dinv, b3, nullptr, nullptr, nullptr,
                                                nullptr, n);
}

// Round 8
// 648.020 us; speedup vs baseline: 5.4330x; 1.1946x over previous
//
#include <hip/hip_runtime.h>

// ---------------------------------------------------------------------------
// 3-layer GCN on MI355X.
// R1: k_gemm `#pragma unroll 2` fixed 3.3GB/dispatch scratch spill (3520->988us).
// R3: dinv pre-scale into GEMM epilogue + agg unroll-4 + pad-4 (988->817us).
// R5: agg unroll-8/pad-8 + gemm de-staged X (817->774us). Unroll 4->8 gave +1%
//     BW (3.77->3.80 TB/s, FETCH const 403MB) => gather stream is at a ~3.8TB/s
//     L2-miss throughput ceiling, NOT latency-bound. Only traffic cuts help.
// R6: bf16 gather table. GEMM computes fp32, writes Hs=bf16(dinv*XW) (25.6MB);
//     agg gathers bf16 (1 uint = 2 cols/lane, same instr count, half bytes),
//     accumulates fp32, writes fp32 O for next GEMM. agg64 packs 2 rows/load
//     (half-wave per row + shfl_xor(32) combine). Predicted FETCH 403->205MB,
//     agg128 122->~70us.
// R7: resubmit of R6 (bench never ran — GPU acquisition timeout).
// ---------------------------------------------------------------------------

__device__ inline unsigned short f2bf(float f) {   // RNE float->bf16
    unsigned int u = __float_as_uint(f);
    u = (u + 0x7FFFu + ((u >> 16) & 1u)) >> 16;
    return (unsigned short)u;
}
__device__ inline float bf_lo(unsigned int u) { return __uint_as_float(u << 16); }
__device__ inline float bf_hi(unsigned int u) { return __uint_as_float(u & 0xFFFF0000u); }

// ---------------- degree ----------------
__global__ __launch_bounds__(256) void k_deg(const int* __restrict__ ei,
                                             int* __restrict__ deg, int E) {
    int e = blockIdx.x * 256 + threadIdx.x;
    if (e < E) atomicAdd(&deg[ei[E + e]], 1);   // dst row of edge_index
}

// dinv + padded degree (round deg up to multiple of 8)
__global__ __launch_bounds__(256) void k_prep(const int* __restrict__ deg,
                                              float* __restrict__ dinv,
                                              int* __restrict__ degp, int n) {
    int i = blockIdx.x * 256 + threadIdx.x;
    if (i < n) {
        int d = deg[i];
        dinv[i] = rsqrtf((float)d + 1.0f);   // +1 self loop
        degp[i] = (d + 7) & ~7;
    }
}

// ---------------- exclusive scan of degp -> row_ptr (2-level) ----------------
__global__ __launch_bounds__(256) void k_scan1(const int* __restrict__ degp,
                                               int* __restrict__ row_ptr,
                                               int* __restrict__ bsums, int n) {
    __shared__ int s[256];
    int i = blockIdx.x * 256 + threadIdx.x;
    int v = (i < n) ? degp[i] : 0;
    s[threadIdx.x] = v;
    __syncthreads();
    for (int off = 1; off < 256; off <<= 1) {
        int add = (threadIdx.x >= off) ? s[threadIdx.x - off] : 0;
        __syncthreads();
        s[threadIdx.x] += add;
        __syncthreads();
    }
    if (i < n) row_ptr[i] = s[threadIdx.x] - v;          // exclusive
    if (threadIdx.x == 255) bsums[blockIdx.x] = s[255];  // block total
}

__global__ __launch_bounds__(512) void k_scan2(const int* __restrict__ bsums,
                                               int* __restrict__ boffs, int nb) {
    __shared__ int s[512];
    int t = threadIdx.x;
    int v = (t < nb) ? bsums[t] : 0;
    s[t] = v;
    __syncthreads();
    for (int off = 1; off < 512; off <<= 1) {
        int add = (t >= off) ? s[t - off] : 0;
        __syncthreads();
        s[t] += add;
        __syncthreads();
    }
    if (t < nb) boffs[t] = s[t] - v;                     // exclusive
}

__global__ __launch_bounds__(256) void k_scan3(int* __restrict__ row_ptr,
                                               const int* __restrict__ boffs, int n) {
    int i = blockIdx.x * 256 + threadIdx.x;
    if (i < n) row_ptr[i] += boffs[blockIdx.x];
}

// ---------------- CSR fill (bucket edges by dst) ----------------
__global__ __launch_bounds__(256) void k_fill(const int* __restrict__ ei,
                                              const int* __restrict__ row_ptr,
                                              int* __restrict__ cursor,
                                              int* __restrict__ csr, int E) {
    int e = blockIdx.x * 256 + threadIdx.x;
    if (e < E) {
        int s = ei[e];
        int d = ei[E + e];
        int p = row_ptr[d] + atomicAdd(&cursor[d], 1);
        csr[p] = s;
    }
}

// pad entries [deg, degp) with sentinel index n (zero row of Hs)
__global__ __launch_bounds__(256) void k_pad(const int* __restrict__ deg,
                                             const int* __restrict__ degp,
                                             const int* __restrict__ row_ptr,
                                             int* __restrict__ csr, int n) {
    int i = blockIdx.x * 256 + threadIdx.x;
    if (i < n) {
        int start = row_ptr[i];
        int d = deg[i], dp = degp[i];
        for (int j = d; j < dp; ++j) csr[start + j] = n;
    }
}

// ---------------- fp32 GEMM -> bf16 table: Hs = bf16(dinv * (X @ W)) --------
// W fully staged in LDS. X read directly from global as ty-group broadcast
// float4 (streams via L1). No per-tile __syncthreads.
template <int DOUT>
__global__ __launch_bounds__(256, (DOUT == 128) ? 2 : 4)
void k_gemm(const float* __restrict__ X, const float* __restrict__ W,
            const float* __restrict__ dinv, unsigned short* __restrict__ H,
            int n, int ntiles) {
    constexpr int CG   = DOUT / 4;        // col groups of 4 (32 or 16)
    constexpr int ROWS = 1024 / CG;       // 32 (DOUT=128) or 64 (DOUT=64)
    __shared__ float Ws[128 * DOUT];

    const int t = threadIdx.x;
    for (int i = t; i < 128 * DOUT; i += 256) Ws[i] = W[i];
    __syncthreads();

    const int tx = t % CG, ty = t / CG;
    const int c0 = tx * 4;

    for (int tile = blockIdx.x; tile < ntiles; tile += gridDim.x) {
        const int rbase = tile * ROWS + ty * 4;
        const float* xr[4];
#pragma unroll
        for (int i = 0; i < 4; i++) {
            int gr = rbase + i;
            xr[i] = X + (size_t)(gr < n ? gr : n - 1) * 128;  // clamp (in-bounds)
        }

        float acc[4][4] = {};
#pragma unroll 2           // R1: cap unroll — full unroll spilled to scratch
        for (int k = 0; k < 128; k += 4) {
            float4 xv[4], wv[4];
#pragma unroll
            for (int i = 0; i < 4; i++)
                xv[i] = *(const float4*)(xr[i] + k);
#pragma unroll
            for (int kk = 0; kk < 4; kk++)
                wv[kk] = *(const float4*)&Ws[(k + kk) * DOUT + c0];
#pragma unroll
            for (int kk = 0; kk < 4; kk++) {
                float w0 = wv[kk].x, w1 = wv[kk].y, w2 = wv[kk].z, w3 = wv[kk].w;
#pragma unroll
                for (int i = 0; i < 4; i++) {
                    float xs = (kk == 0) ? xv[i].x
                             : (kk == 1) ? xv[i].y
                             : (kk == 2) ? xv[i].z
                                         : xv[i].w;
                    acc[i][0] = fmaf(xs, w0, acc[i][0]);
                    acc[i][1] = fmaf(xs, w1, acc[i][1]);
                    acc[i][2] = fmaf(xs, w2, acc[i][2]);
                    acc[i][3] = fmaf(xs, w3, acc[i][3]);
                }
            }
        }
#pragma unroll
        for (int i = 0; i < 4; i++) {
            int gr = rbase + i;
            if (gr < n) {
                float di = dinv[gr];     // R3: pre-scale rows by dinv
                ushort4 s;
                s.x = f2bf(di * acc[i][0]);
                s.y = f2bf(di * acc[i][1]);
                s.z = f2bf(di * acc[i][2]);
                s.w = f2bf(di * acc[i][3]);
                *(ushort4*)&H[(size_t)gr * DOUT + c0] = s;  // 8B coalesced
            }
        }
    }
}

// ---------------- aggregation: 1 wave per node, atomic-free ----------------
// Hs rows are bf16, pre-scaled by dinv.  out_i = dinv_i*(Hs_i + sum Hs_s) + b
// (pad edges -> zero row n).  Accumulate fp32.  Optional BN(eval)+ReLU.
template <int DOUT, bool BNRELU>
__global__ __launch_bounds__(256) void k_agg(
    const unsigned short* __restrict__ Hs, float* __restrict__ O,
    const int* __restrict__ csr, const int* __restrict__ row_ptr,
    const int* __restrict__ degp, const float* __restrict__ dinv,
    const float* __restrict__ bias, const float* __restrict__ gam,
    const float* __restrict__ bet, const float* __restrict__ rm,
    const float* __restrict__ rv, int n) {
    int node = blockIdx.x * 4 + (threadIdx.x >> 6);
    if (node >= n) return;
    int lane  = threadIdx.x & 63;
    int start = row_ptr[node];
    int cntp  = degp[node];             // multiple of 8
    float di  = dinv[node];
    const unsigned int* Hu = (const unsigned int*)Hs;  // 2 bf16 per uint

    if constexpr (DOUT == 128) {
        // row = 64 uints; lane owns cols 2*lane, 2*lane+1
        const int c = lane;
        unsigned int us = Hu[(size_t)node * 64 + c];           // self
        float2 a[8];
        a[0] = make_float2(bf_lo(us), bf_hi(us));
#pragma unroll
        for (int j = 1; j < 8; j++) a[j] = make_float2(0.f, 0.f);
        for (int e = 0; e < cntp; e += 8) {
            int4 sa = *(const int4*)&csr[start + e];
            int4 sb = *(const int4*)&csr[start + e + 4];
            unsigned int u0 = Hu[(size_t)sa.x * 64 + c];
            unsigned int u1 = Hu[(size_t)sa.y * 64 + c];
            unsigned int u2 = Hu[(size_t)sa.z * 64 + c];
            unsigned int u3 = Hu[(size_t)sa.w * 64 + c];
            unsigned int u4 = Hu[(size_t)sb.x * 64 + c];
            unsigned int u5 = Hu[(size_t)sb.y * 64 + c];
            unsigned int u6 = Hu[(size_t)sb.z * 64 + c];
            unsigned int u7 = Hu[(size_t)sb.w * 64 + c];
            a[0].x += bf_lo(u0); a[0].y += bf_hi(u0);
            a[1].x += bf_lo(u1); a[1].y += bf_hi(u1);
            a[2].x += bf_lo(u2); a[2].y += bf_hi(u2);
            a[3].x += bf_lo(u3); a[3].y += bf_hi(u3);
            a[4].x += bf_lo(u4); a[4].y += bf_hi(u4);
            a[5].x += bf_lo(u5); a[5].y += bf_hi(u5);
            a[6].x += bf_lo(u6); a[6].y += bf_hi(u6);
            a[7].x += bf_lo(u7); a[7].y += bf_hi(u7);
        }
        float ax = ((a[0].x + a[1].x) + (a[2].x + a[3].x)) +
                   ((a[4].x + a[5].x) + (a[6].x + a[7].x));
        float ay = ((a[0].y + a[1].y) + (a[2].y + a[3].y)) +
                   ((a[4].y + a[5].y) + (a[6].y + a[7].y));
        int cc = 2 * c;
        float ox = fmaf(di, ax, bias[cc]);
        float oy = fmaf(di, ay, bias[cc + 1]);
        if constexpr (BNRELU) {
            float sx = gam[cc] * rsqrtf(rv[cc] + 1e-5f);
            float sy = gam[cc + 1] * rsqrtf(rv[cc + 1] + 1e-5f);
            ox = fmaxf(fmaf(ox - rm[cc], sx, bet[cc]), 0.f);
            oy = fmaxf(fmaf(oy - rm[cc + 1], sy, bet[cc + 1]), 0.f);
        }
        *(float2*)(O + (size_t)node * 128 + cc) = make_float2(ox, oy);
    } else {  // DOUT == 64: row = 32 uints; 2 rows per load instruction.
        const int half = lane >> 5, cu = lane & 31;   // lane owns cols 2cu,2cu+1
        float2 a0 = {0.f, 0.f}, a1 = {0.f, 0.f}, a2 = {0.f, 0.f}, a3 = {0.f, 0.f};
        for (int e = 0; e < cntp; e += 8) {
            int4 sa = *(const int4*)&csr[start + e];
            int4 sb = *(const int4*)&csr[start + e + 4];
            int i0 = half ? sa.y : sa.x;
            int i1 = half ? sa.w : sa.z;
            int i2 = half ? sb.y : sb.x;
            int i3 = half ? sb.w : sb.z;
            unsigned int u0 = Hu[(size_t)i0 * 32 + cu];
            unsigned int u1 = Hu[(size_t)i1 * 32 + cu];
            unsigned int u2 = Hu[(size_t)i2 * 32 + cu];
            unsigned int u3 = Hu[(size_t)i3 * 32 + cu];
            a0.x += bf_lo(u0); a0.y += bf_hi(u0);
            a1.x += bf_lo(u1); a1.y += bf_hi(u1);
            a2.x += bf_lo(u2); a2.y += bf_hi(u2);
            a3.x += bf_lo(u3); a3.y += bf_hi(u3);
        }
        float sx = (a0.x + a1.x) + (a2.x + a3.x);
        float sy = (a0.y + a1.y) + (a2.y + a3.y);
        // combine the two half-wave partial sums
        sx += __shfl_xor(sx, 32, 64);
        sy += __shfl_xor(sy, 32, 64);
        if (half == 0) {
            unsigned int us = Hu[(size_t)node * 32 + cu];   // self
            sx += bf_lo(us);
            sy += bf_hi(us);
            int cc = 2 * cu;
            float ox = fmaf(di, sx, bias[cc]);
            float oy = fmaf(di, sy, bias[cc + 1]);
            *(float2*)(O + (size_t)node * 64 + cc) = make_float2(ox, oy);
        }
    }
}

// ---------------------------------------------------------------------------
extern "C" void kernel_launch(void* const* d_in, const int* in_sizes, int n_in,
                              void* d_out, int out_size, void* d_ws, size_t ws_size,
                              hipStream_t stream) {
    const float* x   = (const float*)d_in[0];
    const int*   ei  = (const int*)d_in[1];
    const float* W1  = (const float*)d_in[2];
    const float* b1  = (const float*)d_in[3];
    const float* g1  = (const float*)d_in[4];
    const float* be1 = (const float*)d_in[5];
    const float* rm1 = (const float*)d_in[6];
    const float* rv1 = (const float*)d_in[7];
    const float* W2  = (const float*)d_in[8];
    const float* b2  = (const float*)d_in[9];
    const float* g2  = (const float*)d_in[10];
    const float* be2 = (const float*)d_in[11];
    const float* rm2 = (const float*)d_in[12];
    const float* rv2 = (const float*)d_in[13];
    const float* W3  = (const float*)d_in[14];
    const float* b3  = (const float*)d_in[15];

    const int n = in_sizes[0] / 128;
    const int E = in_sizes[1] / 2;

    // ---- workspace carve-up (aligned to 256B) ----
    char*  w   = (char*)d_ws;
    size_t off = 0;
    auto take  = [&](size_t bytes) -> char* {
        char* p = w + off;
        off += (bytes + 255) & ~(size_t)255;
        return p;
    };
    int*   deg    = (int*)take((size_t)n * 4);
    int*   degp   = (int*)take((size_t)n * 4);
    int*   cursor = (int*)take((size_t)n * 4);
    int*   rowp   = (int*)take((size_t)n * 4);
    float* dinv   = (float*)take((size_t)n * 4);
    const int NB  = (n + 255) / 256;
    int*   bsums  = (int*)take((size_t)NB * 4);
    int*   boffs  = (int*)take((size_t)NB * 4);
    int*   csr    = (int*)take((size_t)E * 4 + (size_t)n * 7 * 4 + 64);  // pad-8
    unsigned short* Hs = (unsigned short*)take(((size_t)n + 1) * 128 * 2);  // bf16 table
    float* Of     = (float*)take((size_t)n * 128 * 4);                      // fp32 acts
    (void)ws_size; (void)n_in; (void)out_size;

    // ---- graph preprocessing (identical every call; ws is re-poisoned) ----
    hipMemsetAsync(deg, 0, (size_t)n * 4, stream);
    hipMemsetAsync(cursor, 0, (size_t)n * 4, stream);
    const int egrid = (E + 255) / 256;
    k_deg<<<egrid, 256, 0, stream>>>(ei, deg, E);
    k_prep<<<NB, 256, 0, stream>>>(deg, dinv, degp, n);
    k_scan1<<<NB, 256, 0, stream>>>(degp, rowp, bsums, n);
    k_scan2<<<1, 512, 0, stream>>>(bsums, boffs, NB);
    k_scan3<<<NB, 256, 0, stream>>>(rowp, boffs, n);
    k_fill<<<egrid, 256, 0, stream>>>(ei, rowp, cursor, csr, E);
    k_pad<<<NB, 256, 0, stream>>>(deg, degp, rowp, csr, n);
    // zero sentinel row n of the 128-wide bf16 table (gemm writes rows < n only)
    hipMemsetAsync((char*)Hs + (size_t)n * 256, 0, 256, stream);

    // ---- 3 GCN layers (single Hs table + single fp32 act buffer) ----
    const int nt128 = (n + 31) / 32;
    const int nt64  = (n + 63) / 64;
    const int g128  = nt128 < 512 ? nt128 : 512;
    const int g64   = nt64 < 512 ? nt64 : 512;
    const int agrid = (n + 3) / 4;

    k_gemm<128><<<g128, 256, 0, stream>>>(x, W1, dinv, Hs, n, nt128);
    k_agg<128, true><<<agrid, 256, 0, stream>>>(Hs, Of, csr, rowp, degp, dinv,
                                                b1, g1, be1, rm1, rv1, n);
    k_gemm<128><<<g128, 256, 0, stream>>>(Of, W2, dinv, Hs, n, nt128);
    k_agg<128, true><<<agrid, 256, 0, stream>>>(Hs, Of, csr, rowp, degp, dinv,
                                                b2, g2, be2, rm2, rv2, n);
    k_gemm<64><<<g64, 256, 0, stream>>>(Of, W3, dinv, Hs, n, nt64);
    // zero sentinel row n of the 64-wide table (region held stale 128-wide data)
    hipMemsetAsync((char*)Hs + (size_t)n * 128, 0, 128, stream);
    k_agg<64, false><<<agrid, 256, 0, stream>>>(Hs, (float*)d_out, csr, rowp, degp,
                                                dinv, b3, nullptr, nullptr, nullptr,
                                                nullptr, n);
}

// Round 10
// 568.151 us; speedup vs baseline: 6.1967x; 1.1406x over previous
//
#include <hip/hip_runtime.h>

// ---------------------------------------------------------------------------
// 3-layer GCN on MI355X.
// R1: k_gemm `#pragma unroll 2` fixed 3.3GB/dispatch scratch spill (3520->988us).
// R3: dinv pre-scale into GEMM epilogue + agg unroll-4 + pad-4 (988->817us).
// R5: agg unroll-8/pad-8 + gemm de-staged X (817->774us). Gather stream at
//     ~3.8TB/s L2-miss throughput ceiling -> only traffic cuts help.
// R6: bf16 gather table (774->648us, absmax 2e-3). k_agg now <104us each.
// R8: k_fill dominated (110us: VALU 0.4%, WRITE 103MB = 1.6M scattered 4B
//     stores -> one 64B line WB per edge across non-coherent XCD L2s).
//     Remove fill's atomic pass: k_deg's atomicAdd RETURN is the edge's rank
//     in its dst row -> store rank[e] (ushort, coalesced); fill computes
//     p = rowp[d]+rank[e] atomic-free. A/B: if fill stays ~110 => WB-bound
//     => R10 = XCD-octant binning.
// R9: resubmit of R8 (bench never ran — GPU acquisition timeout).
// ---------------------------------------------------------------------------

__device__ inline unsigned short f2bf(float f) {   // RNE float->bf16
    unsigned int u = __float_as_uint(f);
    u = (u + 0x7FFFu + ((u >> 16) & 1u)) >> 16;
    return (unsigned short)u;
}
__device__ inline float bf_lo(unsigned int u) { return __uint_as_float(u << 16); }
__device__ inline float bf_hi(unsigned int u) { return __uint_as_float(u & 0xFFFF0000u); }

// ---------------- degree + per-edge rank (atomic return value) ----------------
__global__ __launch_bounds__(256) void k_deg(const int* __restrict__ ei,
                                             int* __restrict__ deg,
                                             unsigned short* __restrict__ rank,
                                             int E) {
    int e = blockIdx.x * 256 + threadIdx.x;
    if (e < E)
        rank[e] = (unsigned short)atomicAdd(&deg[ei[E + e]], 1);
}

// dinv + padded degree (round deg up to multiple of 8)
__global__ __launch_bounds__(256) void k_prep(const int* __restrict__ deg,
                                              float* __restrict__ dinv,
                                              int* __restrict__ degp, int n) {
    int i = blockIdx.x * 256 + threadIdx.x;
    if (i < n) {
        int d = deg[i];
        dinv[i] = rsqrtf((float)d + 1.0f);   // +1 self loop
        degp[i] = (d + 7) & ~7;
    }
}

// ---------------- exclusive scan of degp -> row_ptr (2-level) ----------------
__global__ __launch_bounds__(256) void k_scan1(const int* __restrict__ degp,
                                               int* __restrict__ row_ptr,
                                               int* __restrict__ bsums, int n) {
    __shared__ int s[256];
    int i = blockIdx.x * 256 + threadIdx.x;
    int v = (i < n) ? degp[i] : 0;
    s[threadIdx.x] = v;
    __syncthreads();
    for (int off = 1; off < 256; off <<= 1) {
        int add = (threadIdx.x >= off) ? s[threadIdx.x - off] : 0;
        __syncthreads();
        s[threadIdx.x] += add;
        __syncthreads();
    }
    if (i < n) row_ptr[i] = s[threadIdx.x] - v;          // exclusive
    if (threadIdx.x == 255) bsums[blockIdx.x] = s[255];  // block total
}

__global__ __launch_bounds__(512) void k_scan2(const int* __restrict__ bsums,
                                               int* __restrict__ boffs, int nb) {
    __shared__ int s[512];
    int t = threadIdx.x;
    int v = (t < nb) ? bsums[t] : 0;
    s[t] = v;
    __syncthreads();
    for (int off = 1; off < 512; off <<= 1) {
        int add = (t >= off) ? s[t - off] : 0;
        __syncthreads();
        s[t] += add;
        __syncthreads();
    }
    if (t < nb) boffs[t] = s[t] - v;                     // exclusive
}

__global__ __launch_bounds__(256) void k_scan3(int* __restrict__ row_ptr,
                                               const int* __restrict__ boffs, int n) {
    int i = blockIdx.x * 256 + threadIdx.x;
    if (i < n) row_ptr[i] += boffs[blockIdx.x];
}

// ---------------- CSR fill (atomic-free: rank precomputed) ----------------
__global__ __launch_bounds__(256) void k_fill(const int* __restrict__ ei,
                                              const int* __restrict__ row_ptr,
                                              const unsigned short* __restrict__ rank,
                                              int* __restrict__ csr, int E) {
    int e = blockIdx.x * 256 + threadIdx.x;
    if (e < E) {
        int s = ei[e];
        int d = ei[E + e];
        csr[row_ptr[d] + (int)rank[e]] = s;
    }
}

// pad entries [deg, degp) with sentinel index n (zero row of Hs)
__global__ __launch_bounds__(256) void k_pad(const int* __restrict__ deg,
                                             const int* __restrict__ degp,
                                             const int* __restrict__ row_ptr,
                                             int* __restrict__ csr, int n) {
    int i = blockIdx.x * 256 + threadIdx.x;
    if (i < n) {
        int start = row_ptr[i];
        int d = deg[i], dp = degp[i];
        for (int j = d; j < dp; ++j) csr[start + j] = n;
    }
}

// ---------------- fp32 GEMM -> bf16 table: Hs = bf16(dinv * (X @ W)) --------
// W fully staged in LDS. X read directly from global as ty-group broadcast
// float4 (streams via L1). No per-tile __syncthreads.
template <int DOUT>
__global__ __launch_bounds__(256, (DOUT == 128) ? 2 : 4)
void k_gemm(const float* __restrict__ X, const float* __restrict__ W,
            const float* __restrict__ dinv, unsigned short* __restrict__ H,
            int n, int ntiles) {
    constexpr int CG   = DOUT / 4;        // col groups of 4 (32 or 16)
    constexpr int ROWS = 1024 / CG;       // 32 (DOUT=128) or 64 (DOUT=64)
    __shared__ float Ws[128 * DOUT];

    const int t = threadIdx.x;
    for (int i = t; i < 128 * DOUT; i += 256) Ws[i] = W[i];
    __syncthreads();

    const int tx = t % CG, ty = t / CG;
    const int c0 = tx * 4;

    for (int tile = blockIdx.x; tile < ntiles; tile += gridDim.x) {
        const int rbase = tile * ROWS + ty * 4;
        const float* xr[4];
#pragma unroll
        for (int i = 0; i < 4; i++) {
            int gr = rbase + i;
            xr[i] = X + (size_t)(gr < n ? gr : n - 1) * 128;  // clamp (in-bounds)
        }

        float acc[4][4] = {};
#pragma unroll 2           // R1: cap unroll — full unroll spilled to scratch
        for (int k = 0; k < 128; k += 4) {
            float4 xv[4], wv[4];
#pragma unroll
            for (int i = 0; i < 4; i++)
                xv[i] = *(const float4*)(xr[i] + k);
#pragma unroll
            for (int kk = 0; kk < 4; kk++)
                wv[kk] = *(const float4*)&Ws[(k + kk) * DOUT + c0];
#pragma unroll
            for (int kk = 0; kk < 4; kk++) {
                float w0 = wv[kk].x, w1 = wv[kk].y, w2 = wv[kk].z, w3 = wv[kk].w;
#pragma unroll
                for (int i = 0; i < 4; i++) {
                    float xs = (kk == 0) ? xv[i].x
                             : (kk == 1) ? xv[i].y
                             : (kk == 2) ? xv[i].z
                                         : xv[i].w;
                    acc[i][0] = fmaf(xs, w0, acc[i][0]);
                    acc[i][1] = fmaf(xs, w1, acc[i][1]);
                    acc[i][2] = fmaf(xs, w2, acc[i][2]);
                    acc[i][3] = fmaf(xs, w3, acc[i][3]);
                }
            }
        }
#pragma unroll
        for (int i = 0; i < 4; i++) {
            int gr = rbase + i;
            if (gr < n) {
                float di = dinv[gr];     // R3: pre-scale rows by dinv
                ushort4 s;
                s.x = f2bf(di * acc[i][0]);
                s.y = f2bf(di * acc[i][1]);
                s.z = f2bf(di * acc[i][2]);
                s.w = f2bf(di * acc[i][3]);
                *(ushort4*)&H[(size_t)gr * DOUT + c0] = s;  // 8B coalesced
            }
        }
    }
}

// ---------------- aggregation: 1 wave per node, atomic-free ----------------
// Hs rows are bf16, pre-scaled by dinv.  out_i = dinv_i*(Hs_i + sum Hs_s) + b
// (pad edges -> zero row n).  Accumulate fp32.  Optional BN(eval)+ReLU.
template <int DOUT, bool BNRELU>
__global__ __launch_bounds__(256) void k_agg(
    const unsigned short* __restrict__ Hs, float* __restrict__ O,
    const int* __restrict__ csr, const int* __restrict__ row_ptr,
    const int* __restrict__ degp, const float* __restrict__ dinv,
    const float* __restrict__ bias, const float* __restrict__ gam,
    const float* __restrict__ bet, const float* __restrict__ rm,
    const float* __restrict__ rv, int n) {
    int node = blockIdx.x * 4 + (threadIdx.x >> 6);
    if (node >= n) return;
    int lane  = threadIdx.x & 63;
    int start = row_ptr[node];
    int cntp  = degp[node];             // multiple of 8
    float di  = dinv[node];
    const unsigned int* Hu = (const unsigned int*)Hs;  // 2 bf16 per uint

    if constexpr (DOUT == 128) {
        // row = 64 uints; lane owns cols 2*lane, 2*lane+1
        const int c = lane;
        unsigned int us = Hu[(size_t)node * 64 + c];           // self
        float2 a[8];
        a[0] = make_float2(bf_lo(us), bf_hi(us));
#pragma unroll
        for (int j = 1; j < 8; j++) a[j] = make_float2(0.f, 0.f);
        for (int e = 0; e < cntp; e += 8) {
            int4 sa = *(const int4*)&csr[start + e];
            int4 sb = *(const int4*)&csr[start + e + 4];
            unsigned int u0 = Hu[(size_t)sa.x * 64 + c];
            unsigned int u1 = Hu[(size_t)sa.y * 64 + c];
            unsigned int u2 = Hu[(size_t)sa.z * 64 + c];
            unsigned int u3 = Hu[(size_t)sa.w * 64 + c];
            unsigned int u4 = Hu[(size_t)sb.x * 64 + c];
            unsigned int u5 = Hu[(size_t)sb.y * 64 + c];
            unsigned int u6 = Hu[(size_t)sb.z * 64 + c];
            unsigned int u7 = Hu[(size_t)sb.w * 64 + c];
            a[0].x += bf_lo(u0); a[0].y += bf_hi(u0);
            a[1].x += bf_lo(u1); a[1].y += bf_hi(u1);
            a[2].x += bf_lo(u2); a[2].y += bf_hi(u2);
            a[3].x += bf_lo(u3); a[3].y += bf_hi(u3);
            a[4].x += bf_lo(u4); a[4].y += bf_hi(u4);
            a[5].x += bf_lo(u5); a[5].y += bf_hi(u5);
            a[6].x += bf_lo(u6); a[6].y += bf_hi(u6);
            a[7].x += bf_lo(u7); a[7].y += bf_hi(u7);
        }
        float ax = ((a[0].x + a[1].x) + (a[2].x + a[3].x)) +
                   ((a[4].x + a[5].x) + (a[6].x + a[7].x));
        float ay = ((a[0].y + a[1].y) + (a[2].y + a[3].y)) +
                   ((a[4].y + a[5].y) + (a[6].y + a[7].y));
        int cc = 2 * c;
        float ox = fmaf(di, ax, bias[cc]);
        float oy = fmaf(di, ay, bias[cc + 1]);
        if constexpr (BNRELU) {
            float sx = gam[cc] * rsqrtf(rv[cc] + 1e-5f);
            float sy = gam[cc + 1] * rsqrtf(rv[cc + 1] + 1e-5f);
            ox = fmaxf(fmaf(ox - rm[cc], sx, bet[cc]), 0.f);
            oy = fmaxf(fmaf(oy - rm[cc + 1], sy, bet[cc + 1]), 0.f);
        }
        *(float2*)(O + (size_t)node * 128 + cc) = make_float2(ox, oy);
    } else {  // DOUT == 64: row = 32 uints; 2 rows per load instruction.
        const int half = lane >> 5, cu = lane & 31;   // lane owns cols 2cu,2cu+1
        float2 a0 = {0.f, 0.f}, a1 = {0.f, 0.f}, a2 = {0.f, 0.f}, a3 = {0.f, 0.f};
        for (int e = 0; e < cntp; e += 8) {
            int4 sa = *(const int4*)&csr[start + e];
            int4 sb = *(const int4*)&csr[start + e + 4];
            int i0 = half ? sa.y : sa.x;
            int i1 = half ? sa.w : sa.z;
            int i2 = half ? sb.y : sb.x;
            int i3 = half ? sb.w : sb.z;
            unsigned int u0 = Hu[(size_t)i0 * 32 + cu];
            unsigned int u1 = Hu[(size_t)i1 * 32 + cu];
            unsigned int u2 = Hu[(size_t)i2 * 32 + cu];
            unsigned int u3 = Hu[(size_t)i3 * 32 + cu];
            a0.x += bf_lo(u0); a0.y += bf_hi(u0);
            a1.x += bf_lo(u1); a1.y += bf_hi(u1);
            a2.x += bf_lo(u2); a2.y += bf_hi(u2);
            a3.x += bf_lo(u3); a3.y += bf_hi(u3);
        }
        float sx = (a0.x + a1.x) + (a2.x + a3.x);
        float sy = (a0.y + a1.y) + (a2.y + a3.y);
        // combine the two half-wave partial sums
        sx += __shfl_xor(sx, 32, 64);
        sy += __shfl_xor(sy, 32, 64);
        if (half == 0) {
            unsigned int us = Hu[(size_t)node * 32 + cu];   // self
            sx += bf_lo(us);
            sy += bf_hi(us);
            int cc = 2 * cu;
            float ox = fmaf(di, sx, bias[cc]);
            float oy = fmaf(di, sy, bias[cc + 1]);
            *(float2*)(O + (size_t)node * 64 + cc) = make_float2(ox, oy);
        }
    }
}

// ---------------------------------------------------------------------------
extern "C" void kernel_launch(void* const* d_in, const int* in_sizes, int n_in,
                              void* d_out, int out_size, void* d_ws, size_t ws_size,
                              hipStream_t stream) {
    const float* x   = (const float*)d_in[0];
    const int*   ei  = (const int*)d_in[1];
    const float* W1  = (const float*)d_in[2];
    const float* b1  = (const float*)d_in[3];
    const float* g1  = (const float*)d_in[4];
    const float* be1 = (const float*)d_in[5];
    const float* rm1 = (const float*)d_in[6];
    const float* rv1 = (const float*)d_in[7];
    const float* W2  = (const float*)d_in[8];
    const float* b2  = (const float*)d_in[9];
    const float* g2  = (const float*)d_in[10];
    const float* be2 = (const float*)d_in[11];
    const float* rm2 = (const float*)d_in[12];
    const float* rv2 = (const float*)d_in[13];
    const float* W3  = (const float*)d_in[14];
    const float* b3  = (const float*)d_in[15];

    const int n = in_sizes[0] / 128;
    const int E = in_sizes[1] / 2;

    // ---- workspace carve-up (aligned to 256B) ----
    char*  w   = (char*)d_ws;
    size_t off = 0;
    auto take  = [&](size_t bytes) -> char* {
        char* p = w + off;
        off += (bytes + 255) & ~(size_t)255;
        return p;
    };
    int*   deg    = (int*)take((size_t)n * 4);
    int*   degp   = (int*)take((size_t)n * 4);
    int*   rowp   = (int*)take((size_t)n * 4);
    float* dinv   = (float*)take((size_t)n * 4);
    unsigned short* rank = (unsigned short*)take((size_t)E * 2);
    const int NB  = (n + 255) / 256;
    int*   bsums  = (int*)take((size_t)NB * 4);
    int*   boffs  = (int*)take((size_t)NB * 4);
    int*   csr    = (int*)take((size_t)E * 4 + (size_t)n * 7 * 4 + 64);  // pad-8
    unsigned short* Hs = (unsigned short*)take(((size_t)n + 1) * 128 * 2);  // bf16 table
    float* Of     = (float*)take((size_t)n * 128 * 4);                      // fp32 acts
    (void)ws_size; (void)n_in; (void)out_size;

    // ---- graph preprocessing (identical every call; ws is re-poisoned) ----
    hipMemsetAsync(deg, 0, (size_t)n * 4, stream);
    const int egrid = (E + 255) / 256;
    k_deg<<<egrid, 256, 0, stream>>>(ei, deg, rank, E);
    k_prep<<<NB, 256, 0, stream>>>(deg, dinv, degp, n);
    k_scan1<<<NB, 256, 0, stream>>>(degp, rowp, bsums, n);
    k_scan2<<<1, 512, 0, stream>>>(bsums, boffs, NB);
    k_scan3<<<NB, 256, 0, stream>>>(rowp, boffs, n);
    k_fill<<<egrid, 256, 0, stream>>>(ei, rowp, rank, csr, E);
    k_pad<<<NB, 256, 0, stream>>>(deg, degp, rowp, csr, n);
    // zero sentinel row n of the 128-wide bf16 table (gemm writes rows < n only)
    hipMemsetAsync((char*)Hs + (size_t)n * 256, 0, 256, stream);

    // ---- 3 GCN layers (single Hs table + single fp32 act buffer) ----
    const int nt128 = (n + 31) / 32;
    const int nt64  = (n + 63) / 64;
    const int g128  = nt128 < 512 ? nt128 : 512;
    const int g64   = nt64 < 512 ? nt64 : 512;
    const int agrid = (n + 3) / 4;

    k_gemm<128><<<g128, 256, 0, stream>>>(x, W1, dinv, Hs, n, nt128);
    k_agg<128, true><<<agrid, 256, 0, stream>>>(Hs, Of, csr, rowp, degp, dinv,
                                                b1, g1, be1, rm1, rv1, n);
    k_gemm<128><<<g128, 256, 0, stream>>>(Of, W2, dinv, Hs, n, nt128);
    k_agg<128, true><<<agrid, 256, 0, stream>>>(Hs, Of, csr, rowp, degp, dinv,
                                                b2, g2, be2, rm2, rv2, n);
    k_gemm<64><<<g64, 256, 0, stream>>>(Of, W3, dinv, Hs, n, nt64);
    // zero sentinel row n of the 64-wide table (region held stale 128-wide data)
    hipMemsetAsync((char*)Hs + (size_t)n * 128, 0, 128, stream);
    k_agg<64, false><<<agrid, 256, 0, stream>>>(Hs, (float*)d_out, csr, rowp, degp,
                                                dinv, b3, nullptr, nullptr, nullptr,
                                                nullptr, n);
}

// Round 12
// 482.553 us; speedup vs baseline: 7.2959x; 1.1774x over previous
//
#include <hip/hip_runtime.h>

// ---------------------------------------------------------------------------
// 3-layer GCN on MI355X.
// R1: k_gemm `#pragma unroll 2` fixed 3.3GB/dispatch scratch spill (3520->988us).
// R3: dinv pre-scale into GEMM epilogue + agg unroll-4 + pad-4 (988->817us).
// R5: agg unroll-8/pad-8 + gemm de-staged X (817->774us); gather stream at
//     ~3.8TB/s fabric ceiling -> only traffic cuts help.
// R6: bf16 gather table (774->648us, absmax 2e-3).
// R8: atomic-free CSR fill via rank-from-k_deg (648->568us). k_fill was
//     atomic-chain-bound, confirmed.
// R10: fp32 vector GEMM was 84us@39TF, VALUBusy 34%, Occ 18.5%, MfmaUtil 0.
//     Replace with split-bf16 MFMA: X=Xh+Xl, W=Wh+Wl (bf16 RNE + residual),
//     acc = Xh@Wh + Xh@Wl + Xl@Wh (fp32 acc; dropped XlWl ~ 2^-18) via
//     mfma_f32_16x16x32_bf16. W pre-transposed+split once (k_wprep); agg
//     writes split Xh/Xl directly (same bytes as fp32); layer-1 splits fp32
//     x during LDS staging. Frag map (m89-verified): A row=l&15 k=8*(l>>4)+j;
//     B col=l&15; D col=l&15 row=4*(l>>4)+r.
// R11: resubmit of R10 (bench never ran — GPU acquisition timeout).
// ---------------------------------------------------------------------------

typedef short     bf16x8 __attribute__((ext_vector_type(8)));
typedef float     f32x4  __attribute__((ext_vector_type(4)));
typedef unsigned short us8 __attribute__((ext_vector_type(8)));
typedef unsigned short us4 __attribute__((ext_vector_type(4)));
typedef unsigned short us2 __attribute__((ext_vector_type(2)));

__device__ inline unsigned short f2bf(float f) {   // RNE float->bf16
    unsigned int u = __float_as_uint(f);
    u = (u + 0x7FFFu + ((u >> 16) & 1u)) >> 16;
    return (unsigned short)u;
}
__device__ inline float bf2f(unsigned short h) {
    return __uint_as_float(((unsigned int)h) << 16);
}
__device__ inline float bf_lo(unsigned int u) { return __uint_as_float(u << 16); }
__device__ inline float bf_hi(unsigned int u) { return __uint_as_float(u & 0xFFFF0000u); }

// ---------------- degree + per-edge rank (atomic return value) --------------
__global__ __launch_bounds__(256) void k_deg(const int* __restrict__ ei,
                                             int* __restrict__ deg,
                                             unsigned short* __restrict__ rank,
                                             int E) {
    int e = blockIdx.x * 256 + threadIdx.x;
    if (e < E)
        rank[e] = (unsigned short)atomicAdd(&deg[ei[E + e]], 1);
}

__global__ __launch_bounds__(256) void k_prep(const int* __restrict__ deg,
                                              float* __restrict__ dinv,
                                              int* __restrict__ degp, int n) {
    int i = blockIdx.x * 256 + threadIdx.x;
    if (i < n) {
        int d = deg[i];
        dinv[i] = rsqrtf((float)d + 1.0f);   // +1 self loop
        degp[i] = (d + 7) & ~7;
    }
}

// ---------------- exclusive scan of degp -> row_ptr (2-level) ---------------
__global__ __launch_bounds__(256) void k_scan1(const int* __restrict__ degp,
                                               int* __restrict__ row_ptr,
                                               int* __restrict__ bsums, int n) {
    __shared__ int s[256];
    int i = blockIdx.x * 256 + threadIdx.x;
    int v = (i < n) ? degp[i] : 0;
    s[threadIdx.x] = v;
    __syncthreads();
    for (int off = 1; off < 256; off <<= 1) {
        int add = (threadIdx.x >= off) ? s[threadIdx.x - off] : 0;
        __syncthreads();
        s[threadIdx.x] += add;
        __syncthreads();
    }
    if (i < n) row_ptr[i] = s[threadIdx.x] - v;          // exclusive
    if (threadIdx.x == 255) bsums[blockIdx.x] = s[255];  // block total
}

__global__ __launch_bounds__(512) void k_scan2(const int* __restrict__ bsums,
                                               int* __restrict__ boffs, int nb) {
    __shared__ int s[512];
    int t = threadIdx.x;
    int v = (t < nb) ? bsums[t] : 0;
    s[t] = v;
    __syncthreads();
    for (int off = 1; off < 512; off <<= 1) {
        int add = (t >= off) ? s[t - off] : 0;
        __syncthreads();
        s[t] += add;
        __syncthreads();
    }
    if (t < nb) boffs[t] = s[t] - v;                     // exclusive
}

__global__ __launch_bounds__(256) void k_scan3(int* __restrict__ row_ptr,
                                               const int* __restrict__ boffs, int n) {
    int i = blockIdx.x * 256 + threadIdx.x;
    if (i < n) row_ptr[i] += boffs[blockIdx.x];
}

// ---------------- CSR fill (atomic-free: rank precomputed) ------------------
__global__ __launch_bounds__(256) void k_fill(const int* __restrict__ ei,
                                              const int* __restrict__ row_ptr,
                                              const unsigned short* __restrict__ rank,
                                              int* __restrict__ csr, int E) {
    int e = blockIdx.x * 256 + threadIdx.x;
    if (e < E) {
        int s = ei[e];
        int d = ei[E + e];
        csr[row_ptr[d] + (int)rank[e]] = s;
    }
}

__global__ __launch_bounds__(256) void k_pad(const int* __restrict__ deg,
                                             const int* __restrict__ degp,
                                             const int* __restrict__ row_ptr,
                                             int* __restrict__ csr, int n) {
    int i = blockIdx.x * 256 + threadIdx.x;
    if (i < n) {
        int start = row_ptr[i];
        int d = deg[i], dp = degp[i];
        for (int j = d; j < dp; ++j) csr[start + j] = n;
    }
}

// ---------------- W prep: fp32 [128][N] -> bf16 hi/lo TRANSPOSED [N][128] ---
template <int N>
__global__ __launch_bounds__(256) void k_wprep(const float* __restrict__ W,
                                               unsigned short* __restrict__ WhT,
                                               unsigned short* __restrict__ WlT) {
    int tid = blockIdx.x * 256 + threadIdx.x;
    if (tid < 128 * N) {
        int k = tid / N, c = tid % N;
        float v = W[tid];
        unsigned short h = f2bf(v);
        unsigned short l = f2bf(v - bf2f(h));
        WhT[c * 128 + k] = h;
        WlT[c * 128 + k] = l;
    }
}

// ---------------- split-bf16 MFMA GEMM ----------------
// Hs[n][DOUT] = bf16( dinv * (X[n][128] @ W[128][DOUT]) )
// Tile: 32 rows x 64 cols / block; DOUT=128 -> 2 col-halves (blockIdx&1).
// 4 waves: wave w -> rows (w>>1)*16, cols (w&1)*32 (2 frags of 16x16).
// LDS (+8-pad rows): Xh/Xl[32][136], Wh/Wl[64][136] = 51KB -> 3 blocks/CU.
template <int DOUT, bool FP32IN>
__global__ __launch_bounds__(256, 3)
void k_gemm_mfma(const float* __restrict__ Xf,            // FP32IN: fp32 [n][128]
                 const unsigned short* __restrict__ Xhg,  // else: bf16 hi
                 const unsigned short* __restrict__ Xlg,  // else: bf16 lo
                 const unsigned short* __restrict__ WhT,  // [DOUT][128]
                 const unsigned short* __restrict__ WlT,
                 const float* __restrict__ dinv,
                 unsigned short* __restrict__ H, int n, int nrt) {
    constexpr int CH = DOUT / 64;        // col-halves (2 or 1)
    __shared__ unsigned short Xh[32 * 136], Xl[32 * 136];
    __shared__ unsigned short Wh[64 * 136], Wl[64 * 136];

    const int t  = threadIdx.x;
    const int ch = (CH == 2) ? (blockIdx.x & 1) : 0;

    // ---- stage W^T slice (once per block): rows ch*64 .. ch*64+63 ----
#pragma unroll
    for (int i = 0; i < 4; i++) {            // 1024 chunks of ushort8
        int c = t + i * 256;
        int row = c >> 4, s = c & 15;        // 16 chunks per 128-short row
        *(us8*)&Wh[row * 136 + s * 8] =
            *(const us8*)&WhT[(ch * 64 + row) * 128 + s * 8];
        *(us8*)&Wl[row * 136 + s * 8] =
            *(const us8*)&WlT[(ch * 64 + row) * 128 + s * 8];
    }

    const int lane = t & 63;
    const int w    = t >> 6;
    const int wrow = (w >> 1) * 16;
    const int wcol = (w & 1) * 32;
    const int arow = wrow + (lane & 15);
    const int koff = (lane >> 4) * 8;

    const int rt0    = (CH == 2) ? (blockIdx.x >> 1) : blockIdx.x;
    const int rtstep = (CH == 2) ? (gridDim.x >> 1) : gridDim.x;

    for (int rt = rt0; rt < nrt; rt += rtstep) {
        const int rbase = rt * 32;
        __syncthreads();   // protect LDS from previous iteration's readers

        // ---- stage X tile (rows rbase..rbase+31), split to hi/lo ----
        if constexpr (FP32IN) {
#pragma unroll
            for (int i = 0; i < 4; i++) {            // 1024 float4 chunks
                int c = t + i * 256;
                int row = c >> 5, s4 = c & 31;       // 32 float4 per row
                int gr = rbase + row;
                float4 v = *(const float4*)&Xf[(size_t)(gr < n ? gr : n - 1) * 128 + s4 * 4];
                us4 h, l;
                h.x = f2bf(v.x); l.x = f2bf(v.x - bf2f(h.x));
                h.y = f2bf(v.y); l.y = f2bf(v.y - bf2f(h.y));
                h.z = f2bf(v.z); l.z = f2bf(v.z - bf2f(h.z));
                h.w = f2bf(v.w); l.w = f2bf(v.w - bf2f(h.w));
                *(us4*)&Xh[row * 136 + s4 * 4] = h;
                *(us4*)&Xl[row * 136 + s4 * 4] = l;
            }
        } else {
#pragma unroll
            for (int i = 0; i < 2; i++) {            // 512 ushort8 chunks
                int c = t + i * 256;
                int row = c >> 4, s = c & 15;
                int gr = rbase + row;
                size_t gb = (size_t)(gr < n ? gr : n - 1) * 128 + s * 8;
                *(us8*)&Xh[row * 136 + s * 8] = *(const us8*)&Xhg[gb];
                *(us8*)&Xl[row * 136 + s * 8] = *(const us8*)&Xlg[gb];
            }
        }
        __syncthreads();

        // ---- A fragments (16 rows x K=128, hi+lo) ----
        bf16x8 ah[4], al[4];
#pragma unroll
        for (int kk = 0; kk < 4; kk++) {
            ah[kk] = *(const bf16x8*)&Xh[arow * 136 + kk * 32 + koff];
            al[kk] = *(const bf16x8*)&Xl[arow * 136 + kk * 32 + koff];
        }

        // ---- 2 col-frags: acc = AhBh + AhBl + AlBh ----
        f32x4 acc[2];
#pragma unroll
        for (int f = 0; f < 2; f++) {
            const int col = wcol + f * 16 + (lane & 15);
            bf16x8 bh[4], bl[4];
#pragma unroll
            for (int kk = 0; kk < 4; kk++) {
                bh[kk] = *(const bf16x8*)&Wh[col * 136 + kk * 32 + koff];
                bl[kk] = *(const bf16x8*)&Wl[col * 136 + kk * 32 + koff];
            }
            f32x4 a = {0.f, 0.f, 0.f, 0.f};
#pragma unroll
            for (int kk = 0; kk < 4; kk++) {
                a = __builtin_amdgcn_mfma_f32_16x16x32_bf16(ah[kk], bh[kk], a, 0, 0, 0);
                a = __builtin_amdgcn_mfma_f32_16x16x32_bf16(ah[kk], bl[kk], a, 0, 0, 0);
                a = __builtin_amdgcn_mfma_f32_16x16x32_bf16(al[kk], bh[kk], a, 0, 0, 0);
            }
            acc[f] = a;
        }

        // ---- epilogue: Hs[row][col] = bf16(dinv[row] * acc) ----
#pragma unroll
        for (int r = 0; r < 4; r++) {
            int row = rbase + wrow + (lane >> 4) * 4 + r;
            if (row < n) {
                float dv = dinv[row];
                int cb = ch * 64 + wcol + (lane & 15);
                H[(size_t)row * DOUT + cb]      = f2bf(dv * acc[0][r]);
                H[(size_t)row * DOUT + cb + 16] = f2bf(dv * acc[1][r]);
            }
        }
    }
}

// ---------------- aggregation: 1 wave per node, atomic-free -----------------
// Hs rows bf16 pre-scaled by dinv. out_i = dinv_i*(Hs_i + sum Hs_s) + b,
// then BN(eval)+ReLU; DOUT=128 writes SPLIT bf16 (Xh,Xl) for the next MFMA
// GEMM; DOUT=64 writes fp32 d_out.
template <int DOUT, bool BNRELU>
__global__ __launch_bounds__(256) void k_agg(
    const unsigned short* __restrict__ Hs,
    unsigned short* __restrict__ XhB, unsigned short* __restrict__ XlB,
    float* __restrict__ O,
    const int* __restrict__ csr, const int* __restrict__ row_ptr,
    const int* __restrict__ degp, const float* __restrict__ dinv,
    const float* __restrict__ bias, const float* __restrict__ gam,
    const float* __restrict__ bet, const float* __restrict__ rm,
    const float* __restrict__ rv, int n) {
    int node = blockIdx.x * 4 + (threadIdx.x >> 6);
    if (node >= n) return;
    int lane  = threadIdx.x & 63;
    int start = row_ptr[node];
    int cntp  = degp[node];             // multiple of 8
    float di  = dinv[node];
    const unsigned int* Hu = (const unsigned int*)Hs;  // 2 bf16 per uint

    if constexpr (DOUT == 128) {
        const int c = lane;             // uint index: cols 2c, 2c+1
        unsigned int us = Hu[(size_t)node * 64 + c];           // self
        float2 a[8];
        a[0] = make_float2(bf_lo(us), bf_hi(us));
#pragma unroll
        for (int j = 1; j < 8; j++) a[j] = make_float2(0.f, 0.f);
        for (int e = 0; e < cntp; e += 8) {
            int4 sa = *(const int4*)&csr[start + e];
            int4 sb = *(const int4*)&csr[start + e + 4];
            unsigned int u0 = Hu[(size_t)sa.x * 64 + c];
            unsigned int u1 = Hu[(size_t)sa.y * 64 + c];
            unsigned int u2 = Hu[(size_t)sa.z * 64 + c];
            unsigned int u3 = Hu[(size_t)sa.w * 64 + c];
            unsigned int u4 = Hu[(size_t)sb.x * 64 + c];
            unsigned int u5 = Hu[(size_t)sb.y * 64 + c];
            unsigned int u6 = Hu[(size_t)sb.z * 64 + c];
            unsigned int u7 = Hu[(size_t)sb.w * 64 + c];
            a[0].x += bf_lo(u0); a[0].y += bf_hi(u0);
            a[1].x += bf_lo(u1); a[1].y += bf_hi(u1);
            a[2].x += bf_lo(u2); a[2].y += bf_hi(u2);
            a[3].x += bf_lo(u3); a[3].y += bf_hi(u3);
            a[4].x += bf_lo(u4); a[4].y += bf_hi(u4);
            a[5].x += bf_lo(u5); a[5].y += bf_hi(u5);
            a[6].x += bf_lo(u6); a[6].y += bf_hi(u6);
            a[7].x += bf_lo(u7); a[7].y += bf_hi(u7);
        }
        float ax = ((a[0].x + a[1].x) + (a[2].x + a[3].x)) +
                   ((a[4].x + a[5].x) + (a[6].x + a[7].x));
        float ay = ((a[0].y + a[1].y) + (a[2].y + a[3].y)) +
                   ((a[4].y + a[5].y) + (a[6].y + a[7].y));
        int cc = 2 * c;
        float ox = fmaf(di, ax, bias[cc]);
        float oy = fmaf(di, ay, bias[cc + 1]);
        if constexpr (BNRELU) {
            float sx = gam[cc] * rsqrtf(rv[cc] + 1e-5f);
            float sy = gam[cc + 1] * rsqrtf(rv[cc + 1] + 1e-5f);
            ox = fmaxf(fmaf(ox - rm[cc], sx, bet[cc]), 0.f);
            oy = fmaxf(fmaf(oy - rm[cc + 1], sy, bet[cc + 1]), 0.f);
        }
        // split write for next MFMA GEMM (same bytes as one fp32 write)
        us2 h, l;
        h.x = f2bf(ox); l.x = f2bf(ox - bf2f(h.x));
        h.y = f2bf(oy); l.y = f2bf(oy - bf2f(h.y));
        *(us2*)&XhB[(size_t)node * 128 + cc] = h;
        *(us2*)&XlB[(size_t)node * 128 + cc] = l;
    } else {  // DOUT == 64: row = 32 uints; 2 rows per load instruction
        const int half = lane >> 5, cu = lane & 31;
        float2 a0 = {0.f, 0.f}, a1 = {0.f, 0.f}, a2 = {0.f, 0.f}, a3 = {0.f, 0.f};
        for (int e = 0; e < cntp; e += 8) {
            int4 sa = *(const int4*)&csr[start + e];
            int4 sb = *(const int4*)&csr[start + e + 4];
            int i0 = half ? sa.y : sa.x;
            int i1 = half ? sa.w : sa.z;
            int i2 = half ? sb.y : sb.x;
            int i3 = half ? sb.w : sb.z;
            unsigned int u0 = Hu[(size_t)i0 * 32 + cu];
            unsigned int u1 = Hu[(size_t)i1 * 32 + cu];
            unsigned int u2 = Hu[(size_t)i2 * 32 + cu];
            unsigned int u3 = Hu[(size_t)i3 * 32 + cu];
            a0.x += bf_lo(u0); a0.y += bf_hi(u0);
            a1.x += bf_lo(u1); a1.y += bf_hi(u1);
            a2.x += bf_lo(u2); a2.y += bf_hi(u2);
            a3.x += bf_lo(u3); a3.y += bf_hi(u3);
        }
        float sx = (a0.x + a1.x) + (a2.x + a3.x);
        float sy = (a0.y + a1.y) + (a2.y + a3.y);
        sx += __shfl_xor(sx, 32, 64);
        sy += __shfl_xor(sy, 32, 64);
        if (half == 0) {
            unsigned int us = Hu[(size_t)node * 32 + cu];   // self
            sx += bf_lo(us);
            sy += bf_hi(us);
            int cc = 2 * cu;
            float ox = fmaf(di, sx, bias[cc]);
            float oy = fmaf(di, sy, bias[cc + 1]);
            *(float2*)(O + (size_t)node * 64 + cc) = make_float2(ox, oy);
        }
    }
}

// ---------------------------------------------------------------------------
extern "C" void kernel_launch(void* const* d_in, const int* in_sizes, int n_in,
                              void* d_out, int out_size, void* d_ws, size_t ws_size,
                              hipStream_t stream) {
    const float* x   = (const float*)d_in[0];
    const int*   ei  = (const int*)d_in[1];
    const float* W1  = (const float*)d_in[2];
    const float* b1  = (const float*)d_in[3];
    const float* g1  = (const float*)d_in[4];
    const float* be1 = (const float*)d_in[5];
    const float* rm1 = (const float*)d_in[6];
    const float* rv1 = (const float*)d_in[7];
    const float* W2  = (const float*)d_in[8];
    const float* b2  = (const float*)d_in[9];
    const float* g2  = (const float*)d_in[10];
    const float* be2 = (const float*)d_in[11];
    const float* rm2 = (const float*)d_in[12];
    const float* rv2 = (const float*)d_in[13];
    const float* W3  = (const float*)d_in[14];
    const float* b3  = (const float*)d_in[15];

    const int n = in_sizes[0] / 128;
    const int E = in_sizes[1] / 2;

    // ---- workspace carve-up (aligned to 256B) ----
    char*  w   = (char*)d_ws;
    size_t off = 0;
    auto take  = [&](size_t bytes) -> char* {
        char* p = w + off;
        off += (bytes + 255) & ~(size_t)255;
        return p;
    };
    int*   deg    = (int*)take((size_t)n * 4);
    int*   degp   = (int*)take((size_t)n * 4);
    int*   rowp   = (int*)take((size_t)n * 4);
    float* dinv   = (float*)take((size_t)n * 4);
    unsigned short* rank = (unsigned short*)take((size_t)E * 2);
    const int NB  = (n + 255) / 256;
    int*   bsums  = (int*)take((size_t)NB * 4);
    int*   boffs  = (int*)take((size_t)NB * 4);
    int*   csr    = (int*)take((size_t)E * 4 + (size_t)n * 7 * 4 + 64);  // pad-8
    unsigned short* Hs  = (unsigned short*)take(((size_t)n + 1) * 128 * 2);
    unsigned short* Xh  = (unsigned short*)take((size_t)n * 128 * 2);
    unsigned short* Xl  = (unsigned short*)take((size_t)n * 128 * 2);
    unsigned short* Wh1 = (unsigned short*)take(128 * 128 * 2);
    unsigned short* Wl1 = (unsigned short*)take(128 * 128 * 2);
    unsigned short* Wh2 = (unsigned short*)take(128 * 128 * 2);
    unsigned short* Wl2 = (unsigned short*)take(128 * 128 * 2);
    unsigned short* Wh3 = (unsigned short*)take(64 * 128 * 2);
    unsigned short* Wl3 = (unsigned short*)take(64 * 128 * 2);
    (void)ws_size; (void)n_in; (void)out_size;

    // ---- graph preprocessing ----
    hipMemsetAsync(deg, 0, (size_t)n * 4, stream);
    const int egrid = (E + 255) / 256;
    k_deg<<<egrid, 256, 0, stream>>>(ei, deg, rank, E);
    k_prep<<<NB, 256, 0, stream>>>(deg, dinv, degp, n);
    k_scan1<<<NB, 256, 0, stream>>>(degp, rowp, bsums, n);
    k_scan2<<<1, 512, 0, stream>>>(bsums, boffs, NB);
    k_scan3<<<NB, 256, 0, stream>>>(rowp, boffs, n);
    k_fill<<<egrid, 256, 0, stream>>>(ei, rowp, rank, csr, E);
    k_pad<<<NB, 256, 0, stream>>>(deg, degp, rowp, csr, n);
    hipMemsetAsync((char*)Hs + (size_t)n * 256, 0, 256, stream);  // sentinel (128-wide)

    // ---- weight split+transpose (tiny) ----
    k_wprep<128><<<64, 256, 0, stream>>>(W1, Wh1, Wl1);
    k_wprep<128><<<64, 256, 0, stream>>>(W2, Wh2, Wl2);
    k_wprep<64><<<32, 256, 0, stream>>>(W3, Wh3, Wl3);

    // ---- 3 GCN layers ----
    const int nrt   = (n + 31) / 32;
    const int agrid = (n + 3) / 4;

    k_gemm_mfma<128, true><<<512, 256, 0, stream>>>(x, nullptr, nullptr,
                                                    Wh1, Wl1, dinv, Hs, n, nrt);
    k_agg<128, true><<<agrid, 256, 0, stream>>>(Hs, Xh, Xl, nullptr, csr, rowp,
                                                degp, dinv, b1, g1, be1, rm1, rv1, n);
    k_gemm_mfma<128, false><<<512, 256, 0, stream>>>(nullptr, Xh, Xl,
                                                     Wh2, Wl2, dinv, Hs, n, nrt);
    k_agg<128, true><<<agrid, 256, 0, stream>>>(Hs, Xh, Xl, nullptr, csr, rowp,
                                                degp, dinv, b2, g2, be2, rm2, rv2, n);
    k_gemm_mfma<64, false><<<512, 256, 0, stream>>>(nullptr, Xh, Xl,
                                                    Wh3, Wl3, dinv, Hs, n, nrt);
    hipMemsetAsync((char*)Hs + (size_t)n * 128, 0, 128, stream);  // sentinel (64-wide)
    k_agg<64, false><<<agrid, 256, 0, stream>>>(Hs, nullptr, nullptr, (float*)d_out,
                                                csr, rowp, degp, dinv, b3, nullptr,
                                                nullptr, nullptr, nullptr, n);
}

// Round 13
// 475.790 us; speedup vs baseline: 7.3996x; 1.0142x over previous
//
#include <hip/hip_runtime.h>

// ---------------------------------------------------------------------------
// 3-layer GCN on MI355X.
// R1: k_gemm `#pragma unroll 2` fixed 3.3GB/dispatch scratch spill (3520->988us).
// R3: dinv pre-scale into GEMM epilogue + agg unroll-4 + pad-4 (988->817us).
// R5: agg unroll-8/pad-8 + gemm de-staged X (817->774us); gather stream at
//     ~3.8TB/s fabric ceiling -> only traffic cuts help.
// R6: bf16 gather table (774->648us, absmax 2e-3).
// R8: atomic-free CSR fill via rank-from-k_deg (648->568us).
// R10: split-bf16 MFMA GEMM, fp32-class accuracy (568->482us, absmax const).
// R12: k_agg<128> now at 69.4us x2 = 95% of the ~3.8TB/s random-gather
//     ceiling (FETCH 194MB irreducible) — structurally done. Attack the
//     invisible middle (~300us across k_deg/k_fill/gemms):
//     (a) k_deg 4 edges/thread: 4 atomic-with-return chains in flight,
//         coalesced ushort4 rank store (was 1/thread, ~600cy serialized).
//     (b) k_fill 4 edges/thread: 4 scattered stores in flight.
//     (c) gemm grid 512->768 (launch_bounds(256,3) + 51KB LDS = 3 blocks/CU).
// ---------------------------------------------------------------------------

typedef short     bf16x8 __attribute__((ext_vector_type(8)));
typedef float     f32x4  __attribute__((ext_vector_type(4)));
typedef unsigned short us8 __attribute__((ext_vector_type(8)));
typedef unsigned short us4 __attribute__((ext_vector_type(4)));
typedef unsigned short us2 __attribute__((ext_vector_type(2)));

__device__ inline unsigned short f2bf(float f) {   // RNE float->bf16
    unsigned int u = __float_as_uint(f);
    u = (u + 0x7FFFu + ((u >> 16) & 1u)) >> 16;
    return (unsigned short)u;
}
__device__ inline float bf2f(unsigned short h) {
    return __uint_as_float(((unsigned int)h) << 16);
}
__device__ inline float bf_lo(unsigned int u) { return __uint_as_float(u << 16); }
__device__ inline float bf_hi(unsigned int u) { return __uint_as_float(u & 0xFFFF0000u); }

// ---------------- degree + per-edge rank; 4 edges/thread --------------------
__global__ __launch_bounds__(256) void k_deg(const int* __restrict__ ei,
                                             int* __restrict__ deg,
                                             unsigned short* __restrict__ rank,
                                             int E) {
    int e0 = (blockIdx.x * 256 + threadIdx.x) * 4;
    if (e0 + 3 < E) {
        int4 d4 = *(const int4*)&ei[E + e0];
        unsigned short r0 = (unsigned short)atomicAdd(&deg[d4.x], 1);
        unsigned short r1 = (unsigned short)atomicAdd(&deg[d4.y], 1);
        unsigned short r2 = (unsigned short)atomicAdd(&deg[d4.z], 1);
        unsigned short r3 = (unsigned short)atomicAdd(&deg[d4.w], 1);
        us4 r; r.x = r0; r.y = r1; r.z = r2; r.w = r3;
        *(us4*)&rank[e0] = r;
    } else {
        for (int e = e0; e < E; ++e)
            rank[e] = (unsigned short)atomicAdd(&deg[ei[E + e]], 1);
    }
}

__global__ __launch_bounds__(256) void k_prep(const int* __restrict__ deg,
                                              float* __restrict__ dinv,
                                              int* __restrict__ degp, int n) {
    int i = blockIdx.x * 256 + threadIdx.x;
    if (i < n) {
        int d = deg[i];
        dinv[i] = rsqrtf((float)d + 1.0f);   // +1 self loop
        degp[i] = (d + 7) & ~7;
    }
}

// ---------------- exclusive scan of degp -> row_ptr (2-level) ---------------
__global__ __launch_bounds__(256) void k_scan1(const int* __restrict__ degp,
                                               int* __restrict__ row_ptr,
                                               int* __restrict__ bsums, int n) {
    __shared__ int s[256];
    int i = blockIdx.x * 256 + threadIdx.x;
    int v = (i < n) ? degp[i] : 0;
    s[threadIdx.x] = v;
    __syncthreads();
    for (int off = 1; off < 256; off <<= 1) {
        int add = (threadIdx.x >= off) ? s[threadIdx.x - off] : 0;
        __syncthreads();
        s[threadIdx.x] += add;
        __syncthreads();
    }
    if (i < n) row_ptr[i] = s[threadIdx.x] - v;          // exclusive
    if (threadIdx.x == 255) bsums[blockIdx.x] = s[255];  // block total
}

__global__ __launch_bounds__(512) void k_scan2(const int* __restrict__ bsums,
                                               int* __restrict__ boffs, int nb) {
    __shared__ int s[512];
    int t = threadIdx.x;
    int v = (t < nb) ? bsums[t] : 0;
    s[t] = v;
    __syncthreads();
    for (int off = 1; off < 512; off <<= 1) {
        int add = (t >= off) ? s[t - off] : 0;
        __syncthreads();
        s[t] += add;
        __syncthreads();
    }
    if (t < nb) boffs[t] = s[t] - v;                     // exclusive
}

__global__ __launch_bounds__(256) void k_scan3(int* __restrict__ row_ptr,
                                               const int* __restrict__ boffs, int n) {
    int i = blockIdx.x * 256 + threadIdx.x;
    if (i < n) row_ptr[i] += boffs[blockIdx.x];
}

// ---------------- CSR fill (atomic-free); 4 edges/thread --------------------
__global__ __launch_bounds__(256) void k_fill(const int* __restrict__ ei,
                                              const int* __restrict__ row_ptr,
                                              const unsigned short* __restrict__ rank,
                                              int* __restrict__ csr, int E) {
    int e0 = (blockIdx.x * 256 + threadIdx.x) * 4;
    if (e0 + 3 < E) {
        int4 s4 = *(const int4*)&ei[e0];
        int4 d4 = *(const int4*)&ei[E + e0];
        us4  r4 = *(const us4*)&rank[e0];
        csr[row_ptr[d4.x] + (int)r4.x] = s4.x;
        csr[row_ptr[d4.y] + (int)r4.y] = s4.y;
        csr[row_ptr[d4.z] + (int)r4.z] = s4.z;
        csr[row_ptr[d4.w] + (int)r4.w] = s4.w;
    } else {
        for (int e = e0; e < E; ++e)
            csr[row_ptr[ei[E + e]] + (int)rank[e]] = ei[e];
    }
}

__global__ __launch_bounds__(256) void k_pad(const int* __restrict__ deg,
                                             const int* __restrict__ degp,
                                             const int* __restrict__ row_ptr,
                                             int* __restrict__ csr, int n) {
    int i = blockIdx.x * 256 + threadIdx.x;
    if (i < n) {
        int start = row_ptr[i];
        int d = deg[i], dp = degp[i];
        for (int j = d; j < dp; ++j) csr[start + j] = n;
    }
}

// ---------------- W prep: fp32 [128][N] -> bf16 hi/lo TRANSPOSED [N][128] ---
template <int N>
__global__ __launch_bounds__(256) void k_wprep(const float* __restrict__ W,
                                               unsigned short* __restrict__ WhT,
                                               unsigned short* __restrict__ WlT) {
    int tid = blockIdx.x * 256 + threadIdx.x;
    if (tid < 128 * N) {
        int k = tid / N, c = tid % N;
        float v = W[tid];
        unsigned short h = f2bf(v);
        unsigned short l = f2bf(v - bf2f(h));
        WhT[c * 128 + k] = h;
        WlT[c * 128 + k] = l;
    }
}

// ---------------- split-bf16 MFMA GEMM ----------------
// Hs[n][DOUT] = bf16( dinv * (X[n][128] @ W[128][DOUT]) )
// Tile: 32 rows x 64 cols / block; DOUT=128 -> 2 col-halves (blockIdx&1).
// 4 waves: wave w -> rows (w>>1)*16, cols (w&1)*32 (2 frags of 16x16).
// LDS (+8-pad rows): Xh/Xl[32][136], Wh/Wl[64][136] = 51KB -> 3 blocks/CU.
template <int DOUT, bool FP32IN>
__global__ __launch_bounds__(256, 3)
void k_gemm_mfma(const float* __restrict__ Xf,            // FP32IN: fp32 [n][128]
                 const unsigned short* __restrict__ Xhg,  // else: bf16 hi
                 const unsigned short* __restrict__ Xlg,  // else: bf16 lo
                 const unsigned short* __restrict__ WhT,  // [DOUT][128]
                 const unsigned short* __restrict__ WlT,
                 const float* __restrict__ dinv,
                 unsigned short* __restrict__ H, int n, int nrt) {
    constexpr int CH = DOUT / 64;        // col-halves (2 or 1)
    __shared__ unsigned short Xh[32 * 136], Xl[32 * 136];
    __shared__ unsigned short Wh[64 * 136], Wl[64 * 136];

    const int t  = threadIdx.x;
    const int ch = (CH == 2) ? (blockIdx.x & 1) : 0;

    // ---- stage W^T slice (once per block): rows ch*64 .. ch*64+63 ----
#pragma unroll
    for (int i = 0; i < 4; i++) {            // 1024 chunks of ushort8
        int c = t + i * 256;
        int row = c >> 4, s = c & 15;        // 16 chunks per 128-short row
        *(us8*)&Wh[row * 136 + s * 8] =
            *(const us8*)&WhT[(ch * 64 + row) * 128 + s * 8];
        *(us8*)&Wl[row * 136 + s * 8] =
            *(const us8*)&WlT[(ch * 64 + row) * 128 + s * 8];
    }

    const int lane = t & 63;
    const int w    = t >> 6;
    const int wrow = (w >> 1) * 16;
    const int wcol = (w & 1) * 32;
    const int arow = wrow + (lane & 15);
    const int koff = (lane >> 4) * 8;

    const int rt0    = (CH == 2) ? (blockIdx.x >> 1) : blockIdx.x;
    const int rtstep = (CH == 2) ? (gridDim.x >> 1) : gridDim.x;

    for (int rt = rt0; rt < nrt; rt += rtstep) {
        const int rbase = rt * 32;
        __syncthreads();   // protect LDS from previous iteration's readers

        // ---- stage X tile (rows rbase..rbase+31), split to hi/lo ----
        if constexpr (FP32IN) {
#pragma unroll
            for (int i = 0; i < 4; i++) {            // 1024 float4 chunks
                int c = t + i * 256;
                int row = c >> 5, s4 = c & 31;       // 32 float4 per row
                int gr = rbase + row;
                float4 v = *(const float4*)&Xf[(size_t)(gr < n ? gr : n - 1) * 128 + s4 * 4];
                us4 h, l;
                h.x = f2bf(v.x); l.x = f2bf(v.x - bf2f(h.x));
                h.y = f2bf(v.y); l.y = f2bf(v.y - bf2f(h.y));
                h.z = f2bf(v.z); l.z = f2bf(v.z - bf2f(h.z));
                h.w = f2bf(v.w); l.w = f2bf(v.w - bf2f(h.w));
                *(us4*)&Xh[row * 136 + s4 * 4] = h;
                *(us4*)&Xl[row * 136 + s4 * 4] = l;
            }
        } else {
#pragma unroll
            for (int i = 0; i < 2; i++) {            // 512 ushort8 chunks
                int c = t + i * 256;
                int row = c >> 4, s = c & 15;
                int gr = rbase + row;
                size_t gb = (size_t)(gr < n ? gr : n - 1) * 128 + s * 8;
                *(us8*)&Xh[row * 136 + s * 8] = *(const us8*)&Xhg[gb];
                *(us8*)&Xl[row * 136 + s * 8] = *(const us8*)&Xlg[gb];
            }
        }
        __syncthreads();

        // ---- A fragments (16 rows x K=128, hi+lo) ----
        bf16x8 ah[4], al[4];
#pragma unroll
        for (int kk = 0; kk < 4; kk++) {
            ah[kk] = *(const bf16x8*)&Xh[arow * 136 + kk * 32 + koff];
            al[kk] = *(const bf16x8*)&Xl[arow * 136 + kk * 32 + koff];
        }

        // ---- 2 col-frags: acc = AhBh + AhBl + AlBh ----
        f32x4 acc[2];
#pragma unroll
        for (int f = 0; f < 2; f++) {
            const int col = wcol + f * 16 + (lane & 15);
            bf16x8 bh[4], bl[4];
#pragma unroll
            for (int kk = 0; kk < 4; kk++) {
                bh[kk] = *(const bf16x8*)&Wh[col * 136 + kk * 32 + koff];
                bl[kk] = *(const bf16x8*)&Wl[col * 136 + kk * 32 + koff];
            }
            f32x4 a = {0.f, 0.f, 0.f, 0.f};
#pragma unroll
            for (int kk = 0; kk < 4; kk++) {
                a = __builtin_amdgcn_mfma_f32_16x16x32_bf16(ah[kk], bh[kk], a, 0, 0, 0);
                a = __builtin_amdgcn_mfma_f32_16x16x32_bf16(ah[kk], bl[kk], a, 0, 0, 0);
                a = __builtin_amdgcn_mfma_f32_16x16x32_bf16(al[kk], bh[kk], a, 0, 0, 0);
            }
            acc[f] = a;
        }

        // ---- epilogue: Hs[row][col] = bf16(dinv[row] * acc) ----
#pragma unroll
        for (int r = 0; r < 4; r++) {
            int row = rbase + wrow + (lane >> 4) * 4 + r;
            if (row < n) {
                float dv = dinv[row];
                int cb = ch * 64 + wcol + (lane & 15);
                H[(size_t)row * DOUT + cb]      = f2bf(dv * acc[0][r]);
                H[(size_t)row * DOUT + cb + 16] = f2bf(dv * acc[1][r]);
            }
        }
    }
}

// ---------------- aggregation: 1 wave per node, atomic-free -----------------
// Hs rows bf16 pre-scaled by dinv. out_i = dinv_i*(Hs_i + sum Hs_s) + b,
// then BN(eval)+ReLU; DOUT=128 writes SPLIT bf16 (Xh,Xl) for the next MFMA
// GEMM; DOUT=64 writes fp32 d_out.
template <int DOUT, bool BNRELU>
__global__ __launch_bounds__(256) void k_agg(
    const unsigned short* __restrict__ Hs,
    unsigned short* __restrict__ XhB, unsigned short* __restrict__ XlB,
    float* __restrict__ O,
    const int* __restrict__ csr, const int* __restrict__ row_ptr,
    const int* __restrict__ degp, const float* __restrict__ dinv,
    const float* __restrict__ bias, const float* __restrict__ gam,
    const float* __restrict__ bet, const float* __restrict__ rm,
    const float* __restrict__ rv, int n) {
    int node = blockIdx.x * 4 + (threadIdx.x >> 6);
    if (node >= n) return;
    int lane  = threadIdx.x & 63;
    int start = row_ptr[node];
    int cntp  = degp[node];             // multiple of 8
    float di  = dinv[node];
    const unsigned int* Hu = (const unsigned int*)Hs;  // 2 bf16 per uint

    if constexpr (DOUT == 128) {
        const int c = lane;             // uint index: cols 2c, 2c+1
        unsigned int us = Hu[(size_t)node * 64 + c];           // self
        float2 a[8];
        a[0] = make_float2(bf_lo(us), bf_hi(us));
#pragma unroll
        for (int j = 1; j < 8; j++) a[j] = make_float2(0.f, 0.f);
        for (int e = 0; e < cntp; e += 8) {
            int4 sa = *(const int4*)&csr[start + e];
            int4 sb = *(const int4*)&csr[start + e + 4];
            unsigned int u0 = Hu[(size_t)sa.x * 64 + c];
            unsigned int u1 = Hu[(size_t)sa.y * 64 + c];
            unsigned int u2 = Hu[(size_t)sa.z * 64 + c];
            unsigned int u3 = Hu[(size_t)sa.w * 64 + c];
            unsigned int u4 = Hu[(size_t)sb.x * 64 + c];
            unsigned int u5 = Hu[(size_t)sb.y * 64 + c];
            unsigned int u6 = Hu[(size_t)sb.z * 64 + c];
            unsigned int u7 = Hu[(size_t)sb.w * 64 + c];
            a[0].x += bf_lo(u0); a[0].y += bf_hi(u0);
            a[1].x += bf_lo(u1); a[1].y += bf_hi(u1);
            a[2].x += bf_lo(u2); a[2].y += bf_hi(u2);
            a[3].x += bf_lo(u3); a[3].y += bf_hi(u3);
            a[4].x += bf_lo(u4); a[4].y += bf_hi(u4);
            a[5].x += bf_lo(u5); a[5].y += bf_hi(u5);
            a[6].x += bf_lo(u6); a[6].y += bf_hi(u6);
            a[7].x += bf_lo(u7); a[7].y += bf_hi(u7);
        }
        float ax = ((a[0].x + a[1].x) + (a[2].x + a[3].x)) +
                   ((a[4].x + a[5].x) + (a[6].x + a[7].x));
        float ay = ((a[0].y + a[1].y) + (a[2].y + a[3].y)) +
                   ((a[4].y + a[5].y) + (a[6].y + a[7].y));
        int cc = 2 * c;
        float ox = fmaf(di, ax, bias[cc]);
        float oy = fmaf(di, ay, bias[cc + 1]);
        if constexpr (BNRELU) {
            float sx = gam[cc] * rsqrtf(rv[cc] + 1e-5f);
            float sy = gam[cc + 1] * rsqrtf(rv[cc + 1] + 1e-5f);
            ox = fmaxf(fmaf(ox - rm[cc], sx, bet[cc]), 0.f);
            oy = fmaxf(fmaf(oy - rm[cc + 1], sy, bet[cc + 1]), 0.f);
        }
        // split write for next MFMA GEMM (same bytes as one fp32 write)
        us2 h, l;
        h.x = f2bf(ox); l.x = f2bf(ox - bf2f(h.x));
        h.y = f2bf(oy); l.y = f2bf(oy - bf2f(h.y));
        *(us2*)&XhB[(size_t)node * 128 + cc] = h;
        *(us2*)&XlB[(size_t)node * 128 + cc] = l;
    } else {  // DOUT == 64: row = 32 uints; 2 rows per load instruction
        const int half = lane >> 5, cu = lane & 31;
        float2 a0 = {0.f, 0.f}, a1 = {0.f, 0.f}, a2 = {0.f, 0.f}, a3 = {0.f, 0.f};
        for (int e = 0; e < cntp; e += 8) {
            int4 sa = *(const int4*)&csr[start + e];
            int4 sb = *(const int4*)&csr[start + e + 4];
            int i0 = half ? sa.y : sa.x;
            int i1 = half ? sa.w : sa.z;
            int i2 = half ? sb.y : sb.x;
            int i3 = half ? sb.w : sb.z;
            unsigned int u0 = Hu[(size_t)i0 * 32 + cu];
            unsigned int u1 = Hu[(size_t)i1 * 32 + cu];
            unsigned int u2 = Hu[(size_t)i2 * 32 + cu];
            unsigned int u3 = Hu[(size_t)i3 * 32 + cu];
            a0.x += bf_lo(u0); a0.y += bf_hi(u0);
            a1.x += bf_lo(u1); a1.y += bf_hi(u1);
            a2.x += bf_lo(u2); a2.y += bf_hi(u2);
            a3.x += bf_lo(u3); a3.y += bf_hi(u3);
        }
        float sx = (a0.x + a1.x) + (a2.x + a3.x);
        float sy = (a0.y + a1.y) + (a2.y + a3.y);
        sx += __shfl_xor(sx, 32, 64);
        sy += __shfl_xor(sy, 32, 64);
        if (half == 0) {
            unsigned int us = Hu[(size_t)node * 32 + cu];   // self
            sx += bf_lo(us);
            sy += bf_hi(us);
            int cc = 2 * cu;
            float ox = fmaf(di, sx, bias[cc]);
            float oy = fmaf(di, sy, bias[cc + 1]);
            *(float2*)(O + (size_t)node * 64 + cc) = make_float2(ox, oy);
        }
    }
}

// ---------------------------------------------------------------------------
extern "C" void kernel_launch(void* const* d_in, const int* in_sizes, int n_in,
                              void* d_out, int out_size, void* d_ws, size_t ws_size,
                              hipStream_t stream) {
    const float* x   = (const float*)d_in[0];
    const int*   ei  = (const int*)d_in[1];
    const float* W1  = (const float*)d_in[2];
    const float* b1  = (const float*)d_in[3];
    const float* g1  = (const float*)d_in[4];
    const float* be1 = (const float*)d_in[5];
    const float* rm1 = (const float*)d_in[6];
    const float* rv1 = (const float*)d_in[7];
    const float* W2  = (const float*)d_in[8];
    const float* b2  = (const float*)d_in[9];
    const float* g2  = (const float*)d_in[10];
    const float* be2 = (const float*)d_in[11];
    const float* rm2 = (const float*)d_in[12];
    const float* rv2 = (const float*)d_in[13];
    const float* W3  = (const float*)d_in[14];
    const float* b3  = (const float*)d_in[15];

    const int n = in_sizes[0] / 128;
    const int E = in_sizes[1] / 2;

    // ---- workspace carve-up (aligned to 256B) ----
    char*  w   = (char*)d_ws;
    size_t off = 0;
    auto take  = [&](size_t bytes) -> char* {
        char* p = w + off;
        off += (bytes + 255) & ~(size_t)255;
        return p;
    };
    int*   deg    = (int*)take((size_t)n * 4);
    int*   degp   = (int*)take((size_t)n * 4);
    int*   rowp   = (int*)take((size_t)n * 4);
    float* dinv   = (float*)take((size_t)n * 4);
    unsigned short* rank = (unsigned short*)take((size_t)E * 2);
    const int NB  = (n + 255) / 256;
    int*   bsums  = (int*)take((size_t)NB * 4);
    int*   boffs  = (int*)take((size_t)NB * 4);
    int*   csr    = (int*)take((size_t)E * 4 + (size_t)n * 7 * 4 + 64);  // pad-8
    unsigned short* Hs  = (unsigned short*)take(((size_t)n + 1) * 128 * 2);
    unsigned short* Xh  = (unsigned short*)take((size_t)n * 128 * 2);
    unsigned short* Xl  = (unsigned short*)take((size_t)n * 128 * 2);
    unsigned short* Wh1 = (unsigned short*)take(128 * 128 * 2);
    unsigned short* Wl1 = (unsigned short*)take(128 * 128 * 2);
    unsigned short* Wh2 = (unsigned short*)take(128 * 128 * 2);
    unsigned short* Wl2 = (unsigned short*)take(128 * 128 * 2);
    unsigned short* Wh3 = (unsigned short*)take(64 * 128 * 2);
    unsigned short* Wl3 = (unsigned short*)take(64 * 128 * 2);
    (void)ws_size; (void)n_in; (void)out_size;

    // ---- graph preprocessing ----
    hipMemsetAsync(deg, 0, (size_t)n * 4, stream);
    const int egrid4 = (E / 4 + 255) / 256 + 1;   // 4 edges/thread
    k_deg<<<egrid4, 256, 0, stream>>>(ei, deg, rank, E);
    k_prep<<<NB, 256, 0, stream>>>(deg, dinv, degp, n);
    k_scan1<<<NB, 256, 0, stream>>>(degp, rowp, bsums, n);
    k_scan2<<<1, 512, 0, stream>>>(bsums, boffs, NB);
    k_scan3<<<NB, 256, 0, stream>>>(rowp, boffs, n);
    k_fill<<<egrid4, 256, 0, stream>>>(ei, rowp, rank, csr, E);
    k_pad<<<NB, 256, 0, stream>>>(deg, degp, rowp, csr, n);
    hipMemsetAsync((char*)Hs + (size_t)n * 256, 0, 256, stream);  // sentinel (128-wide)

    // ---- weight split+transpose (tiny) ----
    k_wprep<128><<<64, 256, 0, stream>>>(W1, Wh1, Wl1);
    k_wprep<128><<<64, 256, 0, stream>>>(W2, Wh2, Wl2);
    k_wprep<64><<<32, 256, 0, stream>>>(W3, Wh3, Wl3);

    // ---- 3 GCN layers ----
    const int nrt   = (n + 31) / 32;
    const int agrid = (n + 3) / 4;

    k_gemm_mfma<128, true><<<768, 256, 0, stream>>>(x, nullptr, nullptr,
                                                    Wh1, Wl1, dinv, Hs, n, nrt);
    k_agg<128, true><<<agrid, 256, 0, stream>>>(Hs, Xh, Xl, nullptr, csr, rowp,
                                                degp, dinv, b1, g1, be1, rm1, rv1, n);
    k_gemm_mfma<128, false><<<768, 256, 0, stream>>>(nullptr, Xh, Xl,
                                                     Wh2, Wl2, dinv, Hs, n, nrt);
    k_agg<128, true><<<agrid, 256, 0, stream>>>(Hs, Xh, Xl, nullptr, csr, rowp,
                                                degp, dinv, b2, g2, be2, rm2, rv2, n);
    k_gemm_mfma<64, false><<<768, 256, 0, stream>>>(nullptr, Xh, Xl,
                                                    Wh3, Wl3, dinv, Hs, n, nrt);
    hipMemsetAsync((char*)Hs + (size_t)n * 128, 0, 128, stream);  // sentinel (64-wide)
    k_agg<64, false><<<agrid, 256, 0, stream>>>(Hs, nullptr, nullptr, (float*)d_out,
                                                csr, rowp, degp, dinv, b3, nullptr,
                                                nullptr, nullptr, nullptr, n);
}